// Round 1
// baseline (470.566 us; speedup 1.0000x reference)
//
#include <hip/hip_runtime.h>
#include <float.h>

// Model constants (checked against in_sizes at runtime where cheap)
// N=20000, E=320000, F_IN=256, HID=32, HEADS=8, EDGE_DIM=8, HC=256

// ---------------------------------------------------------------- edge embed
// e = relu(edge_attr @ Wse + bse); also accumulate per-dst sums + degree.
__global__ void k_edge_embed(const float* __restrict__ ea, const int* __restrict__ dst,
                             const float* __restrict__ Wse, const float* __restrict__ bse,
                             float* __restrict__ e_emb, float* __restrict__ e_sum,
                             int* __restrict__ deg, int E) {
  int e = blockIdx.x * blockDim.x + threadIdx.x;
  if (e >= E) return;
  float a0 = ea[2 * e], a1 = ea[2 * e + 1];
  int d = dst[e];
#pragma unroll
  for (int j = 0; j < 8; j++) {
    float v = fmaxf(a0 * Wse[j] + a1 * Wse[8 + j] + bse[j], 0.f);
    e_emb[(size_t)e * 8 + j] = v;
    atomicAdd(&e_sum[(size_t)d * 8 + j], v);
  }
  atomicAdd(&deg[d], 1);
}

// e_mean = e_sum / max(deg,1)   (in place on e_sum)
__global__ void k_mean(float* __restrict__ e_sum, const int* __restrict__ deg, int N) {
  int i = blockIdx.x * blockDim.x + threadIdx.x;
  if (i >= N * 8) return;
  int d = deg[i >> 3];
  e_sum[i] = e_sum[i] / (float)(d > 1 ? d : 1);
}

// ---------------------------------------------------------------- CSR build
// Exclusive prefix sum of (deg+1) -> row_ptr. Single block, 1024 threads.
__global__ __launch_bounds__(1024) void k_scan(const int* __restrict__ deg,
                                               int* __restrict__ row_ptr, int N) {
  __shared__ int part[1024];
  int tid = threadIdx.x;
  int chunk = (N + 1023) / 1024;
  int lo = tid * chunk;
  if (lo > N) lo = N;
  int hi = lo + chunk;
  if (hi > N) hi = N;
  int s = 0;
  for (int i = lo; i < hi; i++) s += deg[i] + 1;
  part[tid] = s;
  __syncthreads();
  for (int off = 1; off < 1024; off <<= 1) {
    int v = 0;
    if (tid >= off) v = part[tid - off];
    __syncthreads();
    part[tid] += v;
    __syncthreads();
  }
  int base = part[tid] - s;  // exclusive prefix
  for (int i = lo; i < hi; i++) { row_ptr[i] = base; base += deg[i] + 1; }
  if (tid == 1023) row_ptr[N] = part[1023];
}

// Scatter original edges + self loops (eid = E + n) into CSR order by dst.
__global__ void k_scatter(const int* __restrict__ src, const int* __restrict__ dst,
                          const int* __restrict__ row_ptr, int* __restrict__ cursor,
                          int* __restrict__ csr_src, int* __restrict__ csr_eid,
                          int E, int N) {
  int i = blockIdx.x * blockDim.x + threadIdx.x;
  if (i >= E + N) return;
  int s, d;
  if (i < E) { s = src[i]; d = dst[i]; } else { s = d = i - E; }
  int pos = row_ptr[d] + atomicAdd(&cursor[d], 1);
  csr_src[pos] = s;
  csr_eid[pos] = i;
}

// ---------------------------------------------------------------- GEMM1: h1 = x @ W1
// fp32, 64x64 tile, 4x4 microtile, K chunked by 16.
__global__ __launch_bounds__(256) void k_gemm1(const float* __restrict__ A,
                                               const float* __restrict__ B,
                                               float* __restrict__ C,
                                               int Mdim, int Ndim, int Kdim) {
  __shared__ float As[16 * 65];  // [kk][row], +1 pad
  __shared__ float Bs[16 * 64];  // [kk][col]
  int t = threadIdx.x;
  int tx = t & 15, ty = t >> 4;
  int m0 = blockIdx.x * 64, n0 = blockIdx.y * 64;
  float acc[4][4] = {};
  int arow = t >> 2;        // 0..63
  int ak = (t & 3) * 4;     // 0,4,8,12
  int bk = t >> 4;          // 0..15
  int bcol = (t & 15) * 4;  // 0..60
  for (int k0 = 0; k0 < Kdim; k0 += 16) {
    float4 av = make_float4(0.f, 0.f, 0.f, 0.f);
    if (m0 + arow < Mdim)
      av = *(const float4*)(A + (size_t)(m0 + arow) * Kdim + k0 + ak);
    As[(ak + 0) * 65 + arow] = av.x;
    As[(ak + 1) * 65 + arow] = av.y;
    As[(ak + 2) * 65 + arow] = av.z;
    As[(ak + 3) * 65 + arow] = av.w;
    float4 bv = *(const float4*)(B + (size_t)(k0 + bk) * Ndim + n0 + bcol);
    *(float4*)&Bs[bk * 64 + bcol] = bv;
    __syncthreads();
#pragma unroll
    for (int kk = 0; kk < 16; kk++) {
      float a0 = As[kk * 65 + ty * 4 + 0];
      float a1 = As[kk * 65 + ty * 4 + 1];
      float a2 = As[kk * 65 + ty * 4 + 2];
      float a3 = As[kk * 65 + ty * 4 + 3];
      float4 b = *(const float4*)&Bs[kk * 64 + tx * 4];
      acc[0][0] += a0 * b.x; acc[0][1] += a0 * b.y; acc[0][2] += a0 * b.z; acc[0][3] += a0 * b.w;
      acc[1][0] += a1 * b.x; acc[1][1] += a1 * b.y; acc[1][2] += a1 * b.z; acc[1][3] += a1 * b.w;
      acc[2][0] += a2 * b.x; acc[2][1] += a2 * b.y; acc[2][2] += a2 * b.z; acc[2][3] += a2 * b.w;
      acc[3][0] += a3 * b.x; acc[3][1] += a3 * b.y; acc[3][2] += a3 * b.z; acc[3][3] += a3 * b.w;
    }
    __syncthreads();
  }
#pragma unroll
  for (int i = 0; i < 4; i++) {
    int m = m0 + ty * 4 + i;
    if (m < Mdim) {
      float4 v = make_float4(acc[i][0], acc[i][1], acc[i][2], acc[i][3]);
      *(float4*)(C + (size_t)m * Ndim + n0 + tx * 4) = v;
    }
  }
}

// a_src/a_dst for conv1: per (node, head) dot over 32 channels.
__global__ void k_attn1(const float* __restrict__ h1, const float* __restrict__ as1,
                        const float* __restrict__ ad1, float* __restrict__ asv,
                        float* __restrict__ adv, int N) {
  int i = blockIdx.x * blockDim.x + threadIdx.x;
  if (i >= N * 8) return;
  int n = i >> 3, h = i & 7;
  const float* hp = h1 + (size_t)n * 256 + h * 32;
  const float* ap = as1 + h * 32;
  const float* dp = ad1 + h * 32;
  float s1 = 0.f, s2 = 0.f;
#pragma unroll
  for (int c = 0; c < 32; c++) { float v = hp[c]; s1 += v * ap[c]; s2 += v * dp[c]; }
  asv[i] = s1;
  adv[i] = s2;
}

// Collapse We*ae into M1[8][8] (conv1) and m2[8] (conv2).
__global__ void k_prep(const float* __restrict__ We1, const float* __restrict__ ae1,
                       const float* __restrict__ We2, const float* __restrict__ ae2,
                       float* __restrict__ M1, float* __restrict__ m2) {
  int t = threadIdx.x;
  if (t < 64) {
    int k = t >> 3, h = t & 7;
    float s = 0.f;
    for (int c = 0; c < 32; c++) s += We1[k * 256 + h * 32 + c] * ae1[h * 32 + c];
    M1[k * 8 + h] = s;
  } else if (t < 72) {
    int k = t - 64;
    float s = 0.f;
    for (int c = 0; c < 32; c++) s += We2[k * 32 + c] * ae2[c];
    m2[k] = s;
  }
}

// a_edge for all E+N augmented edges, both layers.
__global__ void k_aedge(const float* __restrict__ e_emb, const float* __restrict__ e_mean,
                        const float* __restrict__ M1, const float* __restrict__ m2,
                        float* __restrict__ aed1, float* __restrict__ aed2, int E, int N) {
  int i = blockIdx.x * blockDim.x + threadIdx.x;
  if (i >= E + N) return;
  const float* ep = (i < E) ? (e_emb + (size_t)i * 8) : (e_mean + (size_t)(i - E) * 8);
  float e8[8];
#pragma unroll
  for (int k = 0; k < 8; k++) e8[k] = ep[k];
#pragma unroll
  for (int h = 0; h < 8; h++) {
    float s = 0.f;
#pragma unroll
    for (int k = 0; k < 8; k++) s += e8[k] * M1[k * 8 + h];
    aed1[(size_t)i * 8 + h] = s;
  }
  float s2 = 0.f;
#pragma unroll
  for (int k = 0; k < 8; k++) s2 += e8[k] * m2[k];
  aed2[i] = s2;
}

// ------------------------------------------------- conv1 gather (block per node)
// Online softmax over in-edges, 8 heads; acc: one channel per thread (256 = H*C).
// Writes h2 = relu(out + b1) directly.
__global__ __launch_bounds__(256) void k_conv1(
    const int* __restrict__ row_ptr, const int* __restrict__ csr_src,
    const int* __restrict__ csr_eid, const float* __restrict__ asv,
    const float* __restrict__ adv, const float* __restrict__ aed1,
    const float* __restrict__ h1, const float* __restrict__ b1,
    float* __restrict__ h2, int N) {
  int n = blockIdx.x;
  int t = threadIdx.x;
  int h = t >> 5;
  __shared__ float sa[64 * 8];
  __shared__ int ssrc[64], seid[64];
  __shared__ float m_s[8], l_s[8], sc_s[8], adv_s[8];
  int begin = row_ptr[n], end = row_ptr[n + 1];
  if (t < 8) { m_s[t] = -FLT_MAX; l_s[t] = 0.f; adv_s[t] = adv[(size_t)n * 8 + t]; }
  float acc = 0.f;
  for (int cs = begin; cs < end; cs += 64) {
    int c = min(64, end - cs);
    __syncthreads();
    if (t < c) { ssrc[t] = csr_src[cs + t]; seid[t] = csr_eid[cs + t]; }
    __syncthreads();
    for (int idx = t; idx < c * 8; idx += 256) {
      int el = idx >> 3, hh = idx & 7;
      float a = asv[(size_t)ssrc[el] * 8 + hh] + adv_s[hh] + aed1[(size_t)seid[el] * 8 + hh];
      a = a > 0.f ? a : 0.2f * a;
      sa[el * 8 + hh] = a;
    }
    __syncthreads();
    if (t < 8) {
      float mm = m_s[t], cm = -FLT_MAX;
      for (int el = 0; el < c; el++) cm = fmaxf(cm, sa[el * 8 + t]);
      float nm = fmaxf(mm, cm);
      float sc = __expf(mm - nm);
      float ls = 0.f;
      for (int el = 0; el < c; el++) {
        float w = __expf(sa[el * 8 + t] - nm);
        sa[el * 8 + t] = w;
        ls += w;
      }
      l_s[t] = l_s[t] * sc + ls;
      m_s[t] = nm;
      sc_s[t] = sc;
    }
    __syncthreads();
    acc *= sc_s[h];
    for (int el = 0; el < c; el++)
      acc += sa[el * 8 + h] * h1[(size_t)ssrc[el] * 256 + t];
  }
  float o = acc / (l_s[h] + 1e-16f) + b1[t];
  h2[(size_t)n * 256 + t] = fmaxf(o, 0.f);
}

// g2 = h2 @ W2  (256 -> 32), 8 nodes per block.
__global__ __launch_bounds__(256) void k_gemm2(const float* __restrict__ h2,
                                               const float* __restrict__ W2,
                                               float* __restrict__ g2, int N) {
  __shared__ float xs[8 * 256];
  int t = threadIdx.x;
  int n0 = blockIdx.x * 8;
  for (int idx = t; idx < 8 * 256; idx += 256) {
    int node = n0 + (idx >> 8);
    xs[idx] = (node < N) ? h2[(size_t)node * 256 + (idx & 255)] : 0.f;
  }
  __syncthreads();
  int j = t >> 5, cc = t & 31;
  int node = n0 + j;
  float acc = 0.f;
#pragma unroll 8
  for (int k = 0; k < 256; k++) acc += xs[j * 256 + k] * W2[k * 32 + cc];
  if (node < N) g2[(size_t)node * 32 + cc] = acc;
}

__global__ void k_attn2(const float* __restrict__ g2, const float* __restrict__ as2,
                        const float* __restrict__ ad2, float* __restrict__ asv2,
                        float* __restrict__ adv2, int N) {
  int n = blockIdx.x * blockDim.x + threadIdx.x;
  if (n >= N) return;
  float s1 = 0.f, s2 = 0.f;
#pragma unroll
  for (int c = 0; c < 32; c++) {
    float v = g2[(size_t)n * 32 + c];
    s1 += v * as2[c];
    s2 += v * ad2[c];
  }
  asv2[n] = s1;
  adv2[n] = s2;
}

// ------------------------------------------------- conv2 gather (wave per node)
__global__ __launch_bounds__(64) void k_conv2(
    const int* __restrict__ row_ptr, const int* __restrict__ csr_src,
    const int* __restrict__ csr_eid, const float* __restrict__ asv2,
    const float* __restrict__ adv2, const float* __restrict__ aed2,
    const float* __restrict__ g2, const float* __restrict__ b2,
    float* __restrict__ out, int N) {
  int n = blockIdx.x;
  int lane = threadIdx.x;
  __shared__ float sw[64];
  __shared__ int ssrc[64];
  int begin = row_ptr[n], end = row_ptr[n + 1];
  float advn = adv2[n];
  float m = -FLT_MAX, l = 0.f, acc = 0.f;
  int cpar = lane >> 5, cc = lane & 31;
  for (int cs = begin; cs < end; cs += 64) {
    int c = min(64, end - cs);
    __syncthreads();
    float a = -FLT_MAX;
    if (lane < c) {
      int s = csr_src[cs + lane];
      ssrc[lane] = s;
      int eid = csr_eid[cs + lane];
      a = asv2[s] + advn + aed2[eid];
      a = a > 0.f ? a : 0.2f * a;
    }
    float cm = a;
    for (int o = 32; o; o >>= 1) cm = fmaxf(cm, __shfl_xor(cm, o));
    float nm = fmaxf(m, cm);
    float sc = __expf(m - nm);
    float w = (lane < c) ? __expf(a - nm) : 0.f;
    float cl = w;
    for (int o = 32; o; o >>= 1) cl += __shfl_xor(cl, o);
    l = l * sc + cl;
    m = nm;
    sw[lane] = w;
    __syncthreads();
    acc *= sc;
    for (int el = cpar; el < c; el += 2)
      acc += sw[el] * g2[(size_t)ssrc[el] * 32 + cc];
  }
  acc += __shfl_xor(acc, 32);
  if (lane < 32) out[(size_t)n * 32 + lane] = acc / (l + 1e-16f) + b2[lane];
}

// ---------------------------------------------------------------- launch
extern "C" void kernel_launch(void* const* d_in, const int* in_sizes, int n_in,
                              void* d_out, int out_size, void* d_ws, size_t ws_size,
                              hipStream_t stream) {
  (void)n_in; (void)out_size; (void)ws_size;
  const float* x   = (const float*)d_in[0];
  const int*   ei  = (const int*)d_in[1];
  const float* ea  = (const float*)d_in[2];
  const float* Wse = (const float*)d_in[3];
  const float* bse = (const float*)d_in[4];
  const float* W1  = (const float*)d_in[5];
  const float* as1 = (const float*)d_in[6];
  const float* ad1 = (const float*)d_in[7];
  const float* We1 = (const float*)d_in[8];
  const float* ae1 = (const float*)d_in[9];
  const float* b1  = (const float*)d_in[10];
  const float* W2  = (const float*)d_in[11];
  const float* as2 = (const float*)d_in[12];
  const float* ad2 = (const float*)d_in[13];
  const float* We2 = (const float*)d_in[14];
  const float* ae2 = (const float*)d_in[15];
  const float* b2  = (const float*)d_in[16];
  const int N = in_sizes[0] / 256;
  const int E = in_sizes[1] / 2;
  const int* src = ei;
  const int* dst = ei + E;

  char* base = (char*)d_ws;
  size_t off = 0;
  auto alloc = [&](size_t bytes) -> char* {
    off = (off + 255) & ~(size_t)255;
    char* p = base + off;
    off += bytes;
    return p;
  };
  // zero region (one memset): e_sum, deg, cursor
  float* e_sum  = (float*)alloc((size_t)N * 8 * 4);
  int*   deg    = (int*)alloc((size_t)N * 4);
  int*   cursor = (int*)alloc((size_t)N * 4);
  size_t zero_bytes = (size_t)((char*)(cursor + N) - (char*)e_sum);
  float* e_emb  = (float*)alloc((size_t)E * 8 * 4);
  int* row_ptr  = (int*)alloc((size_t)(N + 1) * 4);
  int* csr_src  = (int*)alloc((size_t)(E + N) * 4);
  int* csr_eid  = (int*)alloc((size_t)(E + N) * 4);
  float* h1     = (float*)alloc((size_t)N * 256 * 4);
  float* asv1   = (float*)alloc((size_t)N * 8 * 4);
  float* adv1   = (float*)alloc((size_t)N * 8 * 4);
  float* aed1   = (float*)alloc((size_t)(E + N) * 8 * 4);
  float* aed2   = (float*)alloc((size_t)(E + N) * 4);
  float* h2     = (float*)alloc((size_t)N * 256 * 4);
  float* g2     = (float*)alloc((size_t)N * 32 * 4);
  float* asv2   = (float*)alloc((size_t)N * 4);
  float* adv2   = (float*)alloc((size_t)N * 4);
  float* M1     = (float*)alloc(64 * 4);
  float* m2     = (float*)alloc(8 * 4);

  hipMemsetAsync(e_sum, 0, zero_bytes, stream);
  k_edge_embed<<<(E + 255) / 256, 256, 0, stream>>>(ea, dst, Wse, bse, e_emb, e_sum, deg, E);
  k_mean<<<(N * 8 + 255) / 256, 256, 0, stream>>>(e_sum, deg, N);
  k_scan<<<1, 1024, 0, stream>>>(deg, row_ptr, N);
  k_scatter<<<(E + N + 255) / 256, 256, 0, stream>>>(src, dst, row_ptr, cursor, csr_src, csr_eid, E, N);
  dim3 g1((N + 63) / 64, 256 / 64);
  k_gemm1<<<g1, 256, 0, stream>>>(x, W1, h1, N, 256, 256);
  k_attn1<<<(N * 8 + 255) / 256, 256, 0, stream>>>(h1, as1, ad1, asv1, adv1, N);
  k_prep<<<1, 128, 0, stream>>>(We1, ae1, We2, ae2, M1, m2);
  k_aedge<<<(E + N + 255) / 256, 256, 0, stream>>>(e_emb, e_sum, M1, m2, aed1, aed2, E, N);
  k_conv1<<<N, 256, 0, stream>>>(row_ptr, csr_src, csr_eid, asv1, adv1, aed1, h1, b1, h2, N);
  k_gemm2<<<(N + 7) / 8, 256, 0, stream>>>(h2, W2, g2, N);
  k_attn2<<<(N + 255) / 256, 256, 0, stream>>>(g2, as2, ad2, asv2, adv2, N);
  k_conv2<<<N, 64, 0, stream>>>(row_ptr, csr_src, csr_eid, asv2, adv2, aed2, g2, b2, (float*)d_out, N);
}

// Round 2
// 359.221 us; speedup vs baseline: 1.3100x; 1.3100x over previous
//
#include <hip/hip_runtime.h>
#include <float.h>

// Model constants: N=20000, E=320000, F_IN=256, HID=32, HEADS=8, EDGE_DIM=8

// ---------------------------------------------------------------- degree
__global__ void k_deg(const int* __restrict__ dst, int* __restrict__ deg, int E) {
  int e = blockIdx.x * blockDim.x + threadIdx.x;
  if (e < E) atomicAdd(&deg[dst[e]], 1);
}

// ---------------------------------------------------------------- CSR build
// Exclusive prefix sum of (deg+1) -> row_ptr. Single block, 1024 threads.
__global__ __launch_bounds__(1024) void k_scan(const int* __restrict__ deg,
                                               int* __restrict__ row_ptr, int N) {
  __shared__ int part[1024];
  int tid = threadIdx.x;
  int chunk = (N + 1023) / 1024;
  int lo = tid * chunk;
  if (lo > N) lo = N;
  int hi = lo + chunk;
  if (hi > N) hi = N;
  int s = 0;
  for (int i = lo; i < hi; i++) s += deg[i] + 1;
  part[tid] = s;
  __syncthreads();
  for (int off = 1; off < 1024; off <<= 1) {
    int v = 0;
    if (tid >= off) v = part[tid - off];
    __syncthreads();
    part[tid] += v;
    __syncthreads();
  }
  int base = part[tid] - s;  // exclusive prefix
  for (int i = lo; i < hi; i++) { row_ptr[i] = base; base += deg[i] + 1; }
  if (tid == 1023) row_ptr[N] = part[1023];
}

// Scatter original edges + self loops (eid = E + n) into CSR order by dst.
__global__ void k_scatter(const int* __restrict__ src, const int* __restrict__ dst,
                          const int* __restrict__ row_ptr, int* __restrict__ cursor,
                          int* __restrict__ csr_src, int* __restrict__ csr_eid,
                          int E, int N) {
  int i = blockIdx.x * blockDim.x + threadIdx.x;
  if (i >= E + N) return;
  int s, d;
  if (i < E) { s = src[i]; d = dst[i]; } else { s = d = i - E; }
  int pos = row_ptr[d] + atomicAdd(&cursor[d], 1);
  csr_src[pos] = s;
  csr_eid[pos] = i;
}

// ---------------------------------------------------------------- prep
// Collapse We*ae into M1[8][8] (conv1) and m2[8] (conv2).
__global__ void k_prep(const float* __restrict__ We1, const float* __restrict__ ae1,
                       const float* __restrict__ We2, const float* __restrict__ ae2,
                       float* __restrict__ M1, float* __restrict__ m2) {
  int t = threadIdx.x;
  if (t < 64) {
    int k = t >> 3, h = t & 7;
    float s = 0.f;
    for (int c = 0; c < 32; c++) s += We1[k * 256 + h * 32 + c] * ae1[h * 32 + c];
    M1[k * 8 + h] = s;
  } else if (t < 72) {
    int k = t - 64;
    float s = 0.f;
    for (int c = 0; c < 32; c++) s += We2[k * 32 + c] * ae2[c];
    m2[k] = s;
  }
}

// ---------------------------------------------------------------- fused edge logits
// e8 = relu(edge_attr @ Wse + bse); aed1 = e8 @ M1; aed2 = e8 . m2. No atomics.
__global__ void k_edge_fused(const float* __restrict__ ea, const float* __restrict__ Wse,
                             const float* __restrict__ bse, const float* __restrict__ M1,
                             const float* __restrict__ m2,
                             float* __restrict__ aed1, float* __restrict__ aed2, int E) {
  __shared__ float sW[16], sb[8], sM[64], sm2[8];
  int t = threadIdx.x;
  if (t < 16) sW[t] = Wse[t];
  if (t < 8) sb[t] = bse[t];
  if (t < 64) sM[t] = M1[t];
  if (t >= 64 && t < 72) sm2[t - 64] = m2[t - 64];
  __syncthreads();
  int e = blockIdx.x * blockDim.x + t;
  if (e >= E) return;
  float2 av = ((const float2*)ea)[e];
  float e8[8];
#pragma unroll
  for (int k = 0; k < 8; k++)
    e8[k] = fmaxf(av.x * sW[k] + av.y * sW[8 + k] + sb[k], 0.f);
  float o[8];
#pragma unroll
  for (int h = 0; h < 8; h++) {
    float s = 0.f;
#pragma unroll
    for (int k = 0; k < 8; k++) s += e8[k] * sM[k * 8 + h];
    o[h] = s;
  }
  *(float4*)(aed1 + (size_t)e * 8)     = make_float4(o[0], o[1], o[2], o[3]);
  *(float4*)(aed1 + (size_t)e * 8 + 4) = make_float4(o[4], o[5], o[6], o[7]);
  float s2 = 0.f;
#pragma unroll
  for (int k = 0; k < 8; k++) s2 += e8[k] * sm2[k];
  aed2[e] = s2;
}

// Self-loop logits at eid=E+n: mean over CSR row (original edges only) of aed1/aed2.
// 8 threads per node (one per head); head 0 also handles aed2.
__global__ void k_selfmean(const int* __restrict__ row_ptr, const int* __restrict__ csr_eid,
                           float* __restrict__ aed1, float* __restrict__ aed2,
                           int E, int N) {
  int i = blockIdx.x * blockDim.x + threadIdx.x;
  if (i >= N * 8) return;
  int n = i >> 3, h = i & 7;
  int begin = row_ptr[n], end = row_ptr[n + 1];
  int deg = end - begin - 1;  // row includes the self loop
  float inv = 1.f / (float)(deg > 1 ? deg : 1);
  float s = 0.f, s2 = 0.f;
  for (int p = begin; p < end; p++) {
    int eid = csr_eid[p];
    if (eid < E) {
      s += aed1[(size_t)eid * 8 + h];
      if (h == 0) s2 += aed2[eid];
    }
  }
  aed1[(size_t)(E + n) * 8 + h] = s * inv;
  if (h == 0) aed2[E + n] = s2 * inv;
}

// ---------------------------------------------------------------- GEMM1: h1 = x @ W1
__global__ __launch_bounds__(256) void k_gemm1(const float* __restrict__ A,
                                               const float* __restrict__ B,
                                               float* __restrict__ C,
                                               int Mdim, int Ndim, int Kdim) {
  __shared__ float As[16 * 65];  // [kk][row], +1 pad
  __shared__ float Bs[16 * 64];  // [kk][col]
  int t = threadIdx.x;
  int tx = t & 15, ty = t >> 4;
  int m0 = blockIdx.x * 64, n0 = blockIdx.y * 64;
  float acc[4][4] = {};
  int arow = t >> 2;        // 0..63
  int ak = (t & 3) * 4;     // 0,4,8,12
  int bk = t >> 4;          // 0..15
  int bcol = (t & 15) * 4;  // 0..60
  for (int k0 = 0; k0 < Kdim; k0 += 16) {
    float4 av = make_float4(0.f, 0.f, 0.f, 0.f);
    if (m0 + arow < Mdim)
      av = *(const float4*)(A + (size_t)(m0 + arow) * Kdim + k0 + ak);
    As[(ak + 0) * 65 + arow] = av.x;
    As[(ak + 1) * 65 + arow] = av.y;
    As[(ak + 2) * 65 + arow] = av.z;
    As[(ak + 3) * 65 + arow] = av.w;
    float4 bv = *(const float4*)(B + (size_t)(k0 + bk) * Ndim + n0 + bcol);
    *(float4*)&Bs[bk * 64 + bcol] = bv;
    __syncthreads();
#pragma unroll
    for (int kk = 0; kk < 16; kk++) {
      float a0 = As[kk * 65 + ty * 4 + 0];
      float a1 = As[kk * 65 + ty * 4 + 1];
      float a2 = As[kk * 65 + ty * 4 + 2];
      float a3 = As[kk * 65 + ty * 4 + 3];
      float4 b = *(const float4*)&Bs[kk * 64 + tx * 4];
      acc[0][0] += a0 * b.x; acc[0][1] += a0 * b.y; acc[0][2] += a0 * b.z; acc[0][3] += a0 * b.w;
      acc[1][0] += a1 * b.x; acc[1][1] += a1 * b.y; acc[1][2] += a1 * b.z; acc[1][3] += a1 * b.w;
      acc[2][0] += a2 * b.x; acc[2][1] += a2 * b.y; acc[2][2] += a2 * b.z; acc[2][3] += a2 * b.w;
      acc[3][0] += a3 * b.x; acc[3][1] += a3 * b.y; acc[3][2] += a3 * b.z; acc[3][3] += a3 * b.w;
    }
    __syncthreads();
  }
#pragma unroll
  for (int i = 0; i < 4; i++) {
    int m = m0 + ty * 4 + i;
    if (m < Mdim) {
      float4 v = make_float4(acc[i][0], acc[i][1], acc[i][2], acc[i][3]);
      *(float4*)(C + (size_t)m * Ndim + n0 + tx * 4) = v;
    }
  }
}

// a_src/a_dst for conv1: per (node, head) dot over 32 channels.
__global__ void k_attn1(const float* __restrict__ h1, const float* __restrict__ as1,
                        const float* __restrict__ ad1, float* __restrict__ asv,
                        float* __restrict__ adv, int N) {
  int i = blockIdx.x * blockDim.x + threadIdx.x;
  if (i >= N * 8) return;
  int n = i >> 3, h = i & 7;
  const float* hp = h1 + (size_t)n * 256 + h * 32;
  const float* ap = as1 + h * 32;
  const float* dp = ad1 + h * 32;
  float s1 = 0.f, s2 = 0.f;
#pragma unroll
  for (int c = 0; c < 32; c++) { float v = hp[c]; s1 += v * ap[c]; s2 += v * dp[c]; }
  asv[i] = s1;
  adv[i] = s2;
}

// ------------------------------------------------- conv1 gather (block per node)
__global__ __launch_bounds__(256) void k_conv1(
    const int* __restrict__ row_ptr, const int* __restrict__ csr_src,
    const int* __restrict__ csr_eid, const float* __restrict__ asv,
    const float* __restrict__ adv, const float* __restrict__ aed1,
    const float* __restrict__ h1, const float* __restrict__ b1,
    float* __restrict__ h2, int N) {
  int n = blockIdx.x;
  int t = threadIdx.x;
  int h = t >> 5;
  __shared__ float sa[64 * 8];
  __shared__ int ssrc[64], seid[64];
  __shared__ float m_s[8], l_s[8], sc_s[8], adv_s[8];
  int begin = row_ptr[n], end = row_ptr[n + 1];
  if (t < 8) { m_s[t] = -FLT_MAX; l_s[t] = 0.f; adv_s[t] = adv[(size_t)n * 8 + t]; }
  float acc = 0.f;
  for (int cs = begin; cs < end; cs += 64) {
    int c = min(64, end - cs);
    __syncthreads();
    if (t < c) { ssrc[t] = csr_src[cs + t]; seid[t] = csr_eid[cs + t]; }
    __syncthreads();
    for (int idx = t; idx < c * 8; idx += 256) {
      int el = idx >> 3, hh = idx & 7;
      float a = asv[(size_t)ssrc[el] * 8 + hh] + adv_s[hh] + aed1[(size_t)seid[el] * 8 + hh];
      a = a > 0.f ? a : 0.2f * a;
      sa[el * 8 + hh] = a;
    }
    __syncthreads();
    if (t < 8) {
      float mm = m_s[t], cm = -FLT_MAX;
      for (int el = 0; el < c; el++) cm = fmaxf(cm, sa[el * 8 + t]);
      float nm = fmaxf(mm, cm);
      float sc = __expf(mm - nm);
      float ls = 0.f;
      for (int el = 0; el < c; el++) {
        float w = __expf(sa[el * 8 + t] - nm);
        sa[el * 8 + t] = w;
        ls += w;
      }
      l_s[t] = l_s[t] * sc + ls;
      m_s[t] = nm;
      sc_s[t] = sc;
    }
    __syncthreads();
    acc *= sc_s[h];
    for (int el = 0; el < c; el++)
      acc += sa[el * 8 + h] * h1[(size_t)ssrc[el] * 256 + t];
  }
  float o = acc / (l_s[h] + 1e-16f) + b1[t];
  h2[(size_t)n * 256 + t] = fmaxf(o, 0.f);
}

// g2 = h2 @ W2  (256 -> 32), 8 nodes per block.
__global__ __launch_bounds__(256) void k_gemm2(const float* __restrict__ h2,
                                               const float* __restrict__ W2,
                                               float* __restrict__ g2, int N) {
  __shared__ float xs[8 * 256];
  int t = threadIdx.x;
  int n0 = blockIdx.x * 8;
  for (int idx = t; idx < 8 * 256; idx += 256) {
    int node = n0 + (idx >> 8);
    xs[idx] = (node < N) ? h2[(size_t)node * 256 + (idx & 255)] : 0.f;
  }
  __syncthreads();
  int j = t >> 5, cc = t & 31;
  int node = n0 + j;
  float acc = 0.f;
#pragma unroll 8
  for (int k = 0; k < 256; k++) acc += xs[j * 256 + k] * W2[k * 32 + cc];
  if (node < N) g2[(size_t)node * 32 + cc] = acc;
}

__global__ void k_attn2(const float* __restrict__ g2, const float* __restrict__ as2,
                        const float* __restrict__ ad2, float* __restrict__ asv2,
                        float* __restrict__ adv2, int N) {
  int n = blockIdx.x * blockDim.x + threadIdx.x;
  if (n >= N) return;
  float s1 = 0.f, s2 = 0.f;
#pragma unroll
  for (int c = 0; c < 32; c++) {
    float v = g2[(size_t)n * 32 + c];
    s1 += v * as2[c];
    s2 += v * ad2[c];
  }
  asv2[n] = s1;
  adv2[n] = s2;
}

// ------------------------------------------------- conv2 gather (wave per node)
__global__ __launch_bounds__(64) void k_conv2(
    const int* __restrict__ row_ptr, const int* __restrict__ csr_src,
    const int* __restrict__ csr_eid, const float* __restrict__ asv2,
    const float* __restrict__ adv2, const float* __restrict__ aed2,
    const float* __restrict__ g2, const float* __restrict__ b2,
    float* __restrict__ out, int N) {
  int n = blockIdx.x;
  int lane = threadIdx.x;
  __shared__ float sw[64];
  __shared__ int ssrc[64];
  int begin = row_ptr[n], end = row_ptr[n + 1];
  float advn = adv2[n];
  float m = -FLT_MAX, l = 0.f, acc = 0.f;
  int cpar = lane >> 5, cc = lane & 31;
  for (int cs = begin; cs < end; cs += 64) {
    int c = min(64, end - cs);
    __syncthreads();
    float a = -FLT_MAX;
    if (lane < c) {
      int s = csr_src[cs + lane];
      ssrc[lane] = s;
      int eid = csr_eid[cs + lane];
      a = asv2[s] + advn + aed2[eid];
      a = a > 0.f ? a : 0.2f * a;
    }
    float cm = a;
    for (int o = 32; o; o >>= 1) cm = fmaxf(cm, __shfl_xor(cm, o));
    float nm = fmaxf(m, cm);
    float sc = __expf(m - nm);
    float w = (lane < c) ? __expf(a - nm) : 0.f;
    float cl = w;
    for (int o = 32; o; o >>= 1) cl += __shfl_xor(cl, o);
    l = l * sc + cl;
    m = nm;
    sw[lane] = w;
    __syncthreads();
    acc *= sc;
    for (int el = cpar; el < c; el += 2)
      acc += sw[el] * g2[(size_t)ssrc[el] * 32 + cc];
  }
  acc += __shfl_xor(acc, 32);
  if (lane < 32) out[(size_t)n * 32 + lane] = acc / (l + 1e-16f) + b2[lane];
}

// ---------------------------------------------------------------- launch
extern "C" void kernel_launch(void* const* d_in, const int* in_sizes, int n_in,
                              void* d_out, int out_size, void* d_ws, size_t ws_size,
                              hipStream_t stream) {
  (void)n_in; (void)out_size; (void)ws_size;
  const float* x   = (const float*)d_in[0];
  const int*   ei  = (const int*)d_in[1];
  const float* ea  = (const float*)d_in[2];
  const float* Wse = (const float*)d_in[3];
  const float* bse = (const float*)d_in[4];
  const float* W1  = (const float*)d_in[5];
  const float* as1 = (const float*)d_in[6];
  const float* ad1 = (const float*)d_in[7];
  const float* We1 = (const float*)d_in[8];
  const float* ae1 = (const float*)d_in[9];
  const float* b1  = (const float*)d_in[10];
  const float* W2  = (const float*)d_in[11];
  const float* as2 = (const float*)d_in[12];
  const float* ad2 = (const float*)d_in[13];
  const float* We2 = (const float*)d_in[14];
  const float* ae2 = (const float*)d_in[15];
  const float* b2  = (const float*)d_in[16];
  const int N = in_sizes[0] / 256;
  const int E = in_sizes[1] / 2;
  const int* src = ei;
  const int* dst = ei + E;

  char* base = (char*)d_ws;
  size_t off = 0;
  auto alloc = [&](size_t bytes) -> char* {
    off = (off + 255) & ~(size_t)255;
    char* p = base + off;
    off += bytes;
    return p;
  };
  // zero region (one memset): deg, cursor
  int*   deg    = (int*)alloc((size_t)N * 4);
  int*   cursor = (int*)alloc((size_t)N * 4);
  size_t zero_bytes = (size_t)((char*)(cursor + N) - (char*)deg);
  int* row_ptr  = (int*)alloc((size_t)(N + 1) * 4);
  int* csr_src  = (int*)alloc((size_t)(E + N) * 4);
  int* csr_eid  = (int*)alloc((size_t)(E + N) * 4);
  float* h1     = (float*)alloc((size_t)N * 256 * 4);
  float* asv1   = (float*)alloc((size_t)N * 8 * 4);
  float* adv1   = (float*)alloc((size_t)N * 8 * 4);
  float* aed1   = (float*)alloc((size_t)(E + N) * 8 * 4);
  float* aed2   = (float*)alloc((size_t)(E + N) * 4);
  float* h2     = (float*)alloc((size_t)N * 256 * 4);
  float* g2     = (float*)alloc((size_t)N * 32 * 4);
  float* asv2   = (float*)alloc((size_t)N * 4);
  float* adv2   = (float*)alloc((size_t)N * 4);
  float* M1     = (float*)alloc(64 * 4);
  float* m2     = (float*)alloc(8 * 4);

  hipMemsetAsync(deg, 0, zero_bytes, stream);
  k_deg<<<(E + 255) / 256, 256, 0, stream>>>(dst, deg, E);
  k_scan<<<1, 1024, 0, stream>>>(deg, row_ptr, N);
  k_scatter<<<(E + N + 255) / 256, 256, 0, stream>>>(src, dst, row_ptr, cursor, csr_src, csr_eid, E, N);
  k_prep<<<1, 128, 0, stream>>>(We1, ae1, We2, ae2, M1, m2);
  k_edge_fused<<<(E + 255) / 256, 256, 0, stream>>>(ea, Wse, bse, M1, m2, aed1, aed2, E);
  k_selfmean<<<(N * 8 + 255) / 256, 256, 0, stream>>>(row_ptr, csr_eid, aed1, aed2, E, N);
  dim3 g1((N + 63) / 64, 256 / 64);
  k_gemm1<<<g1, 256, 0, stream>>>(x, W1, h1, N, 256, 256);
  k_attn1<<<(N * 8 + 255) / 256, 256, 0, stream>>>(h1, as1, ad1, asv1, adv1, N);
  k_conv1<<<N, 256, 0, stream>>>(row_ptr, csr_src, csr_eid, asv1, adv1, aed1, h1, b1, h2, N);
  k_gemm2<<<(N + 7) / 8, 256, 0, stream>>>(h2, W2, g2, N);
  k_attn2<<<(N + 255) / 256, 256, 0, stream>>>(g2, as2, ad2, asv2, adv2, N);
  k_conv2<<<N, 64, 0, stream>>>(row_ptr, csr_src, csr_eid, asv2, adv2, aed2, g2, b2, (float*)d_out, N);
}

// Round 3
// 322.336 us; speedup vs baseline: 1.4599x; 1.1144x over previous
//
#include <hip/hip_runtime.h>
#include <float.h>

// Model constants: N=20000, E=320000, F_IN=256, HID=32, HEADS=8, EDGE_DIM=8

// ---------------------------------------------------------------- degree
__global__ void k_deg(const int* __restrict__ dst, int* __restrict__ deg, int E) {
  int e = blockIdx.x * blockDim.x + threadIdx.x;
  if (e < E) atomicAdd(&deg[dst[e]], 1);
}

// ---------------------------------------------------------------- CSR build
__global__ __launch_bounds__(1024) void k_scan(const int* __restrict__ deg,
                                               int* __restrict__ row_ptr, int N) {
  __shared__ int part[1024];
  int tid = threadIdx.x;
  int chunk = (N + 1023) / 1024;
  int lo = tid * chunk;
  if (lo > N) lo = N;
  int hi = lo + chunk;
  if (hi > N) hi = N;
  int s = 0;
  for (int i = lo; i < hi; i++) s += deg[i] + 1;
  part[tid] = s;
  __syncthreads();
  for (int off = 1; off < 1024; off <<= 1) {
    int v = 0;
    if (tid >= off) v = part[tid - off];
    __syncthreads();
    part[tid] += v;
    __syncthreads();
  }
  int base = part[tid] - s;  // exclusive prefix
  for (int i = lo; i < hi; i++) { row_ptr[i] = base; base += deg[i] + 1; }
  if (tid == 1023) row_ptr[N] = part[1023];
}

// Scatter edges + self loops into CSR order by dst; aed values go along so the
// hot kernels read them contiguously. Self-loop slot recorded in selfpos[n].
__global__ void k_scatter(const int* __restrict__ src, const int* __restrict__ dst,
                          const int* __restrict__ row_ptr, int* __restrict__ cursor,
                          const float* __restrict__ aed1_lin, const float* __restrict__ aed2_lin,
                          int* __restrict__ csr_src, float* __restrict__ csr_aed1,
                          float* __restrict__ csr_aed2, int* __restrict__ selfpos,
                          int E, int N) {
  int i = blockIdx.x * blockDim.x + threadIdx.x;
  if (i >= E + N) return;
  if (i < E) {
    int d = dst[i];
    int pos = row_ptr[d] + atomicAdd(&cursor[d], 1);
    csr_src[pos] = src[i];
    const float4* a4 = (const float4*)(aed1_lin + (size_t)i * 8);
    *(float4*)(csr_aed1 + (size_t)pos * 8)     = a4[0];
    *(float4*)(csr_aed1 + (size_t)pos * 8 + 4) = a4[1];
    csr_aed2[pos] = aed2_lin[i];
  } else {
    int n = i - E;
    int pos = row_ptr[n] + atomicAdd(&cursor[n], 1);
    csr_src[pos] = n;
    selfpos[n] = pos;  // aed filled later by k_selfmean
  }
}

// ---------------------------------------------------------------- prep
__global__ void k_prep(const float* __restrict__ We1, const float* __restrict__ ae1,
                       const float* __restrict__ We2, const float* __restrict__ ae2,
                       float* __restrict__ M1, float* __restrict__ m2) {
  int t = threadIdx.x;
  if (t < 64) {
    int k = t >> 3, h = t & 7;
    float s = 0.f;
    for (int c = 0; c < 32; c++) s += We1[k * 256 + h * 32 + c] * ae1[h * 32 + c];
    M1[k * 8 + h] = s;
  } else if (t < 72) {
    int k = t - 64;
    float s = 0.f;
    for (int c = 0; c < 32; c++) s += We2[k * 32 + c] * ae2[c];
    m2[k] = s;
  }
}

// ---------------------------------------------------------------- fused edge logits
__global__ void k_edge_fused(const float* __restrict__ ea, const float* __restrict__ Wse,
                             const float* __restrict__ bse, const float* __restrict__ M1,
                             const float* __restrict__ m2,
                             float* __restrict__ aed1, float* __restrict__ aed2, int E) {
  __shared__ float sW[16], sb[8], sM[64], sm2[8];
  int t = threadIdx.x;
  if (t < 16) sW[t] = Wse[t];
  if (t < 8) sb[t] = bse[t];
  if (t < 64) sM[t] = M1[t];
  if (t >= 64 && t < 72) sm2[t - 64] = m2[t - 64];
  __syncthreads();
  int e = blockIdx.x * blockDim.x + t;
  if (e >= E) return;
  float2 av = ((const float2*)ea)[e];
  float e8[8];
#pragma unroll
  for (int k = 0; k < 8; k++)
    e8[k] = fmaxf(av.x * sW[k] + av.y * sW[8 + k] + sb[k], 0.f);
  float o[8];
#pragma unroll
  for (int h = 0; h < 8; h++) {
    float s = 0.f;
#pragma unroll
    for (int k = 0; k < 8; k++) s += e8[k] * sM[k * 8 + h];
    o[h] = s;
  }
  *(float4*)(aed1 + (size_t)e * 8)     = make_float4(o[0], o[1], o[2], o[3]);
  *(float4*)(aed1 + (size_t)e * 8 + 4) = make_float4(o[4], o[5], o[6], o[7]);
  float s2 = 0.f;
#pragma unroll
  for (int k = 0; k < 8; k++) s2 += e8[k] * sm2[k];
  aed2[e] = s2;
}

// Self-loop logits: mean of the row's real-edge logits, written in place at selfpos.
__global__ void k_selfmean(const int* __restrict__ row_ptr, const int* __restrict__ selfpos,
                           float* __restrict__ csr_aed1, float* __restrict__ csr_aed2,
                           int N) {
  int i = blockIdx.x * blockDim.x + threadIdx.x;
  if (i >= N * 8) return;
  int n = i >> 3, h = i & 7;
  int begin = row_ptr[n], end = row_ptr[n + 1];
  int sp = selfpos[n];
  int deg = end - begin - 1;
  float inv = 1.f / (float)(deg > 1 ? deg : 1);
  float s = 0.f, s2 = 0.f;
  for (int p = begin; p < end; p++) {
    if (p == sp) continue;
    s += csr_aed1[(size_t)p * 8 + h];
    if (h == 0) s2 += csr_aed2[p];
  }
  csr_aed1[(size_t)sp * 8 + h] = s * inv;
  if (h == 0) csr_aed2[sp] = s2 * inv;
}

// ---------------------------------------------------------------- GEMM1: h1 = x @ W1
// Fused epilogue: asv/adv (attention source/dst coefficients per head).
__global__ __launch_bounds__(256) void k_gemm1(const float* __restrict__ A,
                                               const float* __restrict__ B,
                                               const float* __restrict__ as1,
                                               const float* __restrict__ ad1,
                                               float* __restrict__ C,
                                               float* __restrict__ asv,
                                               float* __restrict__ adv,
                                               int Mdim, int Ndim, int Kdim) {
  __shared__ float As[16 * 65];
  __shared__ float Bs[16 * 64];
  __shared__ float sas[64], sad[64];
  int t = threadIdx.x;
  int tx = t & 15, ty = t >> 4;
  int m0 = blockIdx.x * 64, n0 = blockIdx.y * 64;
  if (t < 64) { sas[t] = as1[n0 + t]; sad[t] = ad1[n0 + t]; }
  float acc[4][4] = {};
  int arow = t >> 2;
  int ak = (t & 3) * 4;
  int bk = t >> 4;
  int bcol = (t & 15) * 4;
  for (int k0 = 0; k0 < Kdim; k0 += 16) {
    float4 av = make_float4(0.f, 0.f, 0.f, 0.f);
    if (m0 + arow < Mdim)
      av = *(const float4*)(A + (size_t)(m0 + arow) * Kdim + k0 + ak);
    As[(ak + 0) * 65 + arow] = av.x;
    As[(ak + 1) * 65 + arow] = av.y;
    As[(ak + 2) * 65 + arow] = av.z;
    As[(ak + 3) * 65 + arow] = av.w;
    float4 bv = *(const float4*)(B + (size_t)(k0 + bk) * Ndim + n0 + bcol);
    *(float4*)&Bs[bk * 64 + bcol] = bv;
    __syncthreads();
#pragma unroll
    for (int kk = 0; kk < 16; kk++) {
      float a0 = As[kk * 65 + ty * 4 + 0];
      float a1 = As[kk * 65 + ty * 4 + 1];
      float a2 = As[kk * 65 + ty * 4 + 2];
      float a3 = As[kk * 65 + ty * 4 + 3];
      float4 b = *(const float4*)&Bs[kk * 64 + tx * 4];
      acc[0][0] += a0 * b.x; acc[0][1] += a0 * b.y; acc[0][2] += a0 * b.z; acc[0][3] += a0 * b.w;
      acc[1][0] += a1 * b.x; acc[1][1] += a1 * b.y; acc[1][2] += a1 * b.z; acc[1][3] += a1 * b.w;
      acc[2][0] += a2 * b.x; acc[2][1] += a2 * b.y; acc[2][2] += a2 * b.z; acc[2][3] += a2 * b.w;
      acc[3][0] += a3 * b.x; acc[3][1] += a3 * b.y; acc[3][2] += a3 * b.z; acc[3][3] += a3 * b.w;
    }
    __syncthreads();
  }
  int head = (n0 >> 5) + (tx >> 3);
#pragma unroll
  for (int i = 0; i < 4; i++) {
    int m = m0 + ty * 4 + i;
    if (m < Mdim) {
      float4 v = make_float4(acc[i][0], acc[i][1], acc[i][2], acc[i][3]);
      *(float4*)(C + (size_t)m * Ndim + n0 + tx * 4) = v;
    }
    // fused attention coefficients: reduce 32-col head across 8 lanes
    float s1 = acc[i][0] * sas[tx * 4 + 0] + acc[i][1] * sas[tx * 4 + 1] +
               acc[i][2] * sas[tx * 4 + 2] + acc[i][3] * sas[tx * 4 + 3];
    float s2 = acc[i][0] * sad[tx * 4 + 0] + acc[i][1] * sad[tx * 4 + 1] +
               acc[i][2] * sad[tx * 4 + 2] + acc[i][3] * sad[tx * 4 + 3];
#pragma unroll
    for (int o = 1; o < 8; o <<= 1) {
      s1 += __shfl_xor(s1, o);
      s2 += __shfl_xor(s2, o);
    }
    if ((tx & 7) == 0 && m < Mdim) {
      asv[(size_t)m * 8 + head] = s1;
      adv[(size_t)m * 8 + head] = s2;
    }
  }
}

// ------------------------------------------------- conv1: one wave per node
// Parallel online softmax (8 heads) + float4 message accumulation.
__global__ __launch_bounds__(64) void k_conv1(
    const int* __restrict__ row_ptr, const int* __restrict__ csr_src,
    const float* __restrict__ csr_aed1, const float* __restrict__ asv,
    const float* __restrict__ adv, const float* __restrict__ h1,
    const float* __restrict__ b1, float* __restrict__ h2, int N) {
  int n = blockIdx.x;
  int lane = threadIdx.x;
  int h = lane >> 3;   // head for this lane's 4 channels (lane*4 .. lane*4+3)
  int sub = lane & 7;
  __shared__ float sw[64 * 8];
  __shared__ int ssrc[64];
  __shared__ float sm[8], sl[8], sadv[8];
  int begin = row_ptr[n], end = row_ptr[n + 1];
  if (lane < 8) { sm[lane] = -FLT_MAX; sl[lane] = 0.f; sadv[lane] = adv[(size_t)n * 8 + lane]; }
  float4 acc = make_float4(0.f, 0.f, 0.f, 0.f);
  for (int cs = begin; cs < end; cs += 64) {
    int c = min(64, end - cs);
    __syncthreads();
    if (lane < c) ssrc[lane] = csr_src[cs + lane];
    __syncthreads();
    // logits, lane-per-(el,head)
    for (int idx = lane; idx < c * 8; idx += 64) {
      int el = idx >> 3, hh = idx & 7;
      float a = asv[(size_t)ssrc[el] * 8 + hh] + sadv[hh] +
                csr_aed1[(size_t)(cs + el) * 8 + hh];
      a = a > 0.f ? a : 0.2f * a;
      sw[idx] = a;
    }
    __syncthreads();
    // per-head running max
    float mloc = -FLT_MAX;
    for (int el = sub; el < c; el += 8) mloc = fmaxf(mloc, sw[el * 8 + h]);
#pragma unroll
    for (int o = 1; o < 8; o <<= 1) mloc = fmaxf(mloc, __shfl_xor(mloc, o));
    float mold = sm[h];
    float mnew = fmaxf(mold, mloc);
    float scale = __expf(mold - mnew);
    // exp + partial sums
    float lloc = 0.f;
    for (int el = sub; el < c; el += 8) {
      float w = __expf(sw[el * 8 + h] - mnew);
      sw[el * 8 + h] = w;
      lloc += w;
    }
#pragma unroll
    for (int o = 1; o < 8; o <<= 1) lloc += __shfl_xor(lloc, o);
    __syncthreads();
    if (sub == 0) { sm[h] = mnew; sl[h] = sl[h] * scale + lloc; }
    // accumulate (full h1 row per el: 64 lanes x float4 = 1 KB)
    acc.x *= scale; acc.y *= scale; acc.z *= scale; acc.w *= scale;
    for (int el = 0; el < c; el++) {
      float w = sw[el * 8 + h];
      const float4 hv = *(const float4*)(h1 + (size_t)ssrc[el] * 256 + lane * 4);
      acc.x += w * hv.x; acc.y += w * hv.y; acc.z += w * hv.z; acc.w += w * hv.w;
    }
  }
  __syncthreads();
  float inv = 1.f / (sl[h] + 1e-16f);
  float4 bv = *(const float4*)(b1 + lane * 4);
  float4 o4;
  o4.x = fmaxf(acc.x * inv + bv.x, 0.f);
  o4.y = fmaxf(acc.y * inv + bv.y, 0.f);
  o4.z = fmaxf(acc.z * inv + bv.z, 0.f);
  o4.w = fmaxf(acc.w * inv + bv.w, 0.f);
  *(float4*)(h2 + (size_t)n * 256 + lane * 4) = o4;
}

// g2 = h2 @ W2 (256 -> 32), 8 nodes/block; fused asv2/adv2 epilogue.
__global__ __launch_bounds__(256) void k_gemm2(const float* __restrict__ h2,
                                               const float* __restrict__ W2,
                                               const float* __restrict__ as2,
                                               const float* __restrict__ ad2,
                                               float* __restrict__ g2,
                                               float* __restrict__ asv2,
                                               float* __restrict__ adv2, int N) {
  __shared__ float xs[8 * 256];
  __shared__ float sas[32], sad[32];
  int t = threadIdx.x;
  if (t < 32) { sas[t] = as2[t]; sad[t] = ad2[t]; }
  int n0 = blockIdx.x * 8;
  for (int idx = t; idx < 8 * 256; idx += 256) {
    int node = n0 + (idx >> 8);
    xs[idx] = (node < N) ? h2[(size_t)node * 256 + (idx & 255)] : 0.f;
  }
  __syncthreads();
  int j = t >> 5, cc = t & 31;
  int node = n0 + j;
  float acc = 0.f;
#pragma unroll 8
  for (int k = 0; k < 256; k++) acc += xs[j * 256 + k] * W2[k * 32 + cc];
  float s1 = acc * sas[cc], s2 = acc * sad[cc];
#pragma unroll
  for (int o = 1; o < 32; o <<= 1) {
    s1 += __shfl_xor(s1, o);
    s2 += __shfl_xor(s2, o);
  }
  if (node < N) {
    g2[(size_t)node * 32 + cc] = acc;
    if (cc == 0) { asv2[node] = s1; adv2[node] = s2; }
  }
}

// ------------------------------------------------- conv2: one wave per node
__global__ __launch_bounds__(64) void k_conv2(
    const int* __restrict__ row_ptr, const int* __restrict__ csr_src,
    const float* __restrict__ csr_aed2, const float* __restrict__ asv2,
    const float* __restrict__ adv2, const float* __restrict__ g2,
    const float* __restrict__ b2, float* __restrict__ out, int N) {
  int n = blockIdx.x;
  int lane = threadIdx.x;
  int sub = lane >> 3, q = lane & 7;
  __shared__ float sw[64];
  __shared__ int ssrc[64];
  int begin = row_ptr[n], end = row_ptr[n + 1];
  float advn = adv2[n];
  float m = -FLT_MAX, l = 0.f;
  float4 acc = make_float4(0.f, 0.f, 0.f, 0.f);
  for (int cs = begin; cs < end; cs += 64) {
    int c = min(64, end - cs);
    __syncthreads();
    float a = -FLT_MAX;
    if (lane < c) {
      int s = csr_src[cs + lane];
      ssrc[lane] = s;
      a = asv2[s] + advn + csr_aed2[cs + lane];
      a = a > 0.f ? a : 0.2f * a;
    }
    float cm = a;
#pragma unroll
    for (int o = 1; o < 64; o <<= 1) cm = fmaxf(cm, __shfl_xor(cm, o));
    float nm = fmaxf(m, cm);
    float sc = __expf(m - nm);
    float w = (lane < c) ? __expf(a - nm) : 0.f;
    float cl = w;
#pragma unroll
    for (int o = 1; o < 64; o <<= 1) cl += __shfl_xor(cl, o);
    l = l * sc + cl;
    m = nm;
    sw[lane] = w;
    __syncthreads();
    acc.x *= sc; acc.y *= sc; acc.z *= sc; acc.w *= sc;
    for (int el = sub; el < c; el += 8) {
      float w2 = sw[el];
      const float4 gv = *(const float4*)(g2 + (size_t)ssrc[el] * 32 + q * 4);
      acc.x += w2 * gv.x; acc.y += w2 * gv.y; acc.z += w2 * gv.z; acc.w += w2 * gv.w;
    }
  }
#pragma unroll
  for (int o = 8; o < 64; o <<= 1) {
    acc.x += __shfl_xor(acc.x, o);
    acc.y += __shfl_xor(acc.y, o);
    acc.z += __shfl_xor(acc.z, o);
    acc.w += __shfl_xor(acc.w, o);
  }
  if (lane < 8) {
    float inv = 1.f / (l + 1e-16f);
    float4 bv = *(const float4*)(b2 + lane * 4);
    float4 o4;
    o4.x = acc.x * inv + bv.x;
    o4.y = acc.y * inv + bv.y;
    o4.z = acc.z * inv + bv.z;
    o4.w = acc.w * inv + bv.w;
    *(float4*)(out + (size_t)n * 32 + lane * 4) = o4;
  }
}

// ---------------------------------------------------------------- launch
extern "C" void kernel_launch(void* const* d_in, const int* in_sizes, int n_in,
                              void* d_out, int out_size, void* d_ws, size_t ws_size,
                              hipStream_t stream) {
  (void)n_in; (void)out_size; (void)ws_size;
  const float* x   = (const float*)d_in[0];
  const int*   ei  = (const int*)d_in[1];
  const float* ea  = (const float*)d_in[2];
  const float* Wse = (const float*)d_in[3];
  const float* bse = (const float*)d_in[4];
  const float* W1  = (const float*)d_in[5];
  const float* as1 = (const float*)d_in[6];
  const float* ad1 = (const float*)d_in[7];
  const float* We1 = (const float*)d_in[8];
  const float* ae1 = (const float*)d_in[9];
  const float* b1  = (const float*)d_in[10];
  const float* W2  = (const float*)d_in[11];
  const float* as2 = (const float*)d_in[12];
  const float* ad2 = (const float*)d_in[13];
  const float* We2 = (const float*)d_in[14];
  const float* ae2 = (const float*)d_in[15];
  const float* b2  = (const float*)d_in[16];
  const int N = in_sizes[0] / 256;
  const int E = in_sizes[1] / 2;
  const int* src = ei;
  const int* dst = ei + E;

  char* base = (char*)d_ws;
  size_t off = 0;
  auto alloc = [&](size_t bytes) -> char* {
    off = (off + 255) & ~(size_t)255;
    char* p = base + off;
    off += bytes;
    return p;
  };
  int*   deg      = (int*)alloc((size_t)N * 4);
  int*   cursor   = (int*)alloc((size_t)N * 4);
  size_t zero_bytes = (size_t)((char*)(cursor + N) - (char*)deg);
  int* row_ptr    = (int*)alloc((size_t)(N + 1) * 4);
  int* selfpos    = (int*)alloc((size_t)N * 4);
  int* csr_src    = (int*)alloc((size_t)(E + N) * 4);
  float* aed1_lin = (float*)alloc((size_t)E * 8 * 4);
  float* aed2_lin = (float*)alloc((size_t)E * 4);
  float* csr_aed1 = (float*)alloc((size_t)(E + N) * 8 * 4);
  float* csr_aed2 = (float*)alloc((size_t)(E + N) * 4);
  float* h1       = (float*)alloc((size_t)N * 256 * 4);
  float* asv1     = (float*)alloc((size_t)N * 8 * 4);
  float* adv1     = (float*)alloc((size_t)N * 8 * 4);
  float* h2       = (float*)alloc((size_t)N * 256 * 4);
  float* g2       = (float*)alloc((size_t)N * 32 * 4);
  float* asv2     = (float*)alloc((size_t)N * 4);
  float* adv2     = (float*)alloc((size_t)N * 4);
  float* M1       = (float*)alloc(64 * 4);
  float* m2       = (float*)alloc(8 * 4);

  hipMemsetAsync(deg, 0, zero_bytes, stream);
  k_deg<<<(E + 255) / 256, 256, 0, stream>>>(dst, deg, E);
  k_scan<<<1, 1024, 0, stream>>>(deg, row_ptr, N);
  k_prep<<<1, 128, 0, stream>>>(We1, ae1, We2, ae2, M1, m2);
  k_edge_fused<<<(E + 255) / 256, 256, 0, stream>>>(ea, Wse, bse, M1, m2, aed1_lin, aed2_lin, E);
  k_scatter<<<(E + N + 255) / 256, 256, 0, stream>>>(src, dst, row_ptr, cursor,
                                                     aed1_lin, aed2_lin,
                                                     csr_src, csr_aed1, csr_aed2, selfpos, E, N);
  k_selfmean<<<(N * 8 + 255) / 256, 256, 0, stream>>>(row_ptr, selfpos, csr_aed1, csr_aed2, N);
  dim3 g1((N + 63) / 64, 4);
  k_gemm1<<<g1, 256, 0, stream>>>(x, W1, as1, ad1, h1, asv1, adv1, N, 256, 256);
  k_conv1<<<N, 64, 0, stream>>>(row_ptr, csr_src, csr_aed1, asv1, adv1, h1, b1, h2, N);
  k_gemm2<<<(N + 7) / 8, 256, 0, stream>>>(h2, W2, as2, ad2, g2, asv2, adv2, N);
  k_conv2<<<N, 64, 0, stream>>>(row_ptr, csr_src, csr_aed2, asv2, adv2, g2, b2, (float*)d_out, N);
}

// Round 4
// 276.816 us; speedup vs baseline: 1.6999x; 1.1644x over previous
//
#include <hip/hip_runtime.h>
#include <float.h>

// Model constants: N=20000, E=320000, F_IN=256, HID=32, HEADS=8, EDGE_DIM=8

typedef short v8s __attribute__((ext_vector_type(8)));
typedef float v4f __attribute__((ext_vector_type(4)));

__device__ __forceinline__ ushort f2bf(float f) {
  unsigned u = __float_as_uint(f);
  u = (u + 0x7FFF + ((u >> 16) & 1)) >> 16;
  return (ushort)u;
}
__device__ __forceinline__ float bf2f(ushort h) {
  return __uint_as_float(((unsigned)h) << 16);
}

// ---------------------------------------------------------------- degree
__global__ void k_deg(const int* __restrict__ dst, int* __restrict__ deg, int E) {
  int e = blockIdx.x * blockDim.x + threadIdx.x;
  if (e < E) atomicAdd(&deg[dst[e]], 1);
}

// ---------------------------------------------------------------- CSR build
__global__ __launch_bounds__(1024) void k_scan(const int* __restrict__ deg,
                                               int* __restrict__ row_ptr, int N) {
  __shared__ int part[1024];
  int tid = threadIdx.x;
  int chunk = (N + 1023) / 1024;
  int lo = tid * chunk;
  if (lo > N) lo = N;
  int hi = lo + chunk;
  if (hi > N) hi = N;
  int s = 0;
  for (int i = lo; i < hi; i++) s += deg[i] + 1;
  part[tid] = s;
  __syncthreads();
  for (int off = 1; off < 1024; off <<= 1) {
    int v = 0;
    if (tid >= off) v = part[tid - off];
    __syncthreads();
    part[tid] += v;
    __syncthreads();
  }
  int base = part[tid] - s;  // exclusive prefix
  for (int i = lo; i < hi; i++) { row_ptr[i] = base; base += deg[i] + 1; }
  if (tid == 1023) row_ptr[N] = part[1023];
}

// Scatter edges + self loops into CSR order by dst; aed values carried along.
__global__ void k_scatter(const int* __restrict__ src, const int* __restrict__ dst,
                          const int* __restrict__ row_ptr, int* __restrict__ cursor,
                          const float* __restrict__ aed1_lin, const float* __restrict__ aed2_lin,
                          int* __restrict__ csr_src, float* __restrict__ csr_aed1,
                          float* __restrict__ csr_aed2, int* __restrict__ selfpos,
                          int E, int N) {
  int i = blockIdx.x * blockDim.x + threadIdx.x;
  if (i >= E + N) return;
  if (i < E) {
    int d = dst[i];
    int pos = row_ptr[d] + atomicAdd(&cursor[d], 1);
    csr_src[pos] = src[i];
    const float4* a4 = (const float4*)(aed1_lin + (size_t)i * 8);
    *(float4*)(csr_aed1 + (size_t)pos * 8)     = a4[0];
    *(float4*)(csr_aed1 + (size_t)pos * 8 + 4) = a4[1];
    csr_aed2[pos] = aed2_lin[i];
  } else {
    int n = i - E;
    int pos = row_ptr[n] + atomicAdd(&cursor[n], 1);
    csr_src[pos] = n;
    selfpos[n] = pos;  // aed filled later by k_selfmean
  }
}

// ---------------------------------------------------------------- prep
__global__ void k_prep(const float* __restrict__ We1, const float* __restrict__ ae1,
                       const float* __restrict__ We2, const float* __restrict__ ae2,
                       float* __restrict__ M1, float* __restrict__ m2) {
  int t = threadIdx.x;
  if (t < 64) {
    int k = t >> 3, h = t & 7;
    float s = 0.f;
    for (int c = 0; c < 32; c++) s += We1[k * 256 + h * 32 + c] * ae1[h * 32 + c];
    M1[k * 8 + h] = s;
  } else if (t < 72) {
    int k = t - 64;
    float s = 0.f;
    for (int c = 0; c < 32; c++) s += We2[k * 32 + c] * ae2[c];
    m2[k] = s;
  }
}

// W1 [K=256][N=256] fp32 -> W1T [n][k] bf16
__global__ __launch_bounds__(256) void k_transpose(const float* __restrict__ W1,
                                                   ushort* __restrict__ Bt) {
  __shared__ float tile[32][33];
  int bx = blockIdx.x & 7, by = blockIdx.x >> 3;
  int tx = threadIdx.x & 31, ty = threadIdx.x >> 5;
  for (int r = ty; r < 32; r += 8)
    tile[r][tx] = W1[(size_t)(by * 32 + r) * 256 + bx * 32 + tx];
  __syncthreads();
  for (int r = ty; r < 32; r += 8)
    Bt[(size_t)(bx * 32 + r) * 256 + by * 32 + tx] = f2bf(tile[tx][r]);
}

// ---------------------------------------------------------------- fused edge logits
__global__ void k_edge_fused(const float* __restrict__ ea, const float* __restrict__ Wse,
                             const float* __restrict__ bse, const float* __restrict__ M1,
                             const float* __restrict__ m2,
                             float* __restrict__ aed1, float* __restrict__ aed2, int E) {
  __shared__ float sW[16], sb[8], sM[64], sm2[8];
  int t = threadIdx.x;
  if (t < 16) sW[t] = Wse[t];
  if (t < 8) sb[t] = bse[t];
  if (t < 64) sM[t] = M1[t];
  if (t >= 64 && t < 72) sm2[t - 64] = m2[t - 64];
  __syncthreads();
  int e = blockIdx.x * blockDim.x + t;
  if (e >= E) return;
  float2 av = ((const float2*)ea)[e];
  float e8[8];
#pragma unroll
  for (int k = 0; k < 8; k++)
    e8[k] = fmaxf(av.x * sW[k] + av.y * sW[8 + k] + sb[k], 0.f);
  float o[8];
#pragma unroll
  for (int h = 0; h < 8; h++) {
    float s = 0.f;
#pragma unroll
    for (int k = 0; k < 8; k++) s += e8[k] * sM[k * 8 + h];
    o[h] = s;
  }
  *(float4*)(aed1 + (size_t)e * 8)     = make_float4(o[0], o[1], o[2], o[3]);
  *(float4*)(aed1 + (size_t)e * 8 + 4) = make_float4(o[4], o[5], o[6], o[7]);
  float s2 = 0.f;
#pragma unroll
  for (int k = 0; k < 8; k++) s2 += e8[k] * sm2[k];
  aed2[e] = s2;
}

// Self-loop logits: mean of the row's real-edge logits, written at selfpos.
__global__ void k_selfmean(const int* __restrict__ row_ptr, const int* __restrict__ selfpos,
                           float* __restrict__ csr_aed1, float* __restrict__ csr_aed2,
                           int N) {
  int i = blockIdx.x * blockDim.x + threadIdx.x;
  if (i >= N * 8) return;
  int n = i >> 3, h = i & 7;
  int begin = row_ptr[n], end = row_ptr[n + 1];
  int sp = selfpos[n];
  int deg = end - begin - 1;
  float inv = 1.f / (float)(deg > 1 ? deg : 1);
  float s = 0.f, s2 = 0.f;
  for (int p = begin; p < end; p++) {
    if (p == sp) continue;
    s += csr_aed1[(size_t)p * 8 + h];
    if (h == 0) s2 += csr_aed2[p];
  }
  csr_aed1[(size_t)sp * 8 + h] = s * inv;
  if (h == 0) csr_aed2[sp] = s2 * inv;
}

// ---------------------------------------------------------------- GEMM1 (MFMA bf16)
// h1b = bf16(x @ W1). 64 rows x 256 cols per block; 4 waves, each 64 cols.
__global__ __launch_bounds__(256) void k_gemm1_mfma(const float* __restrict__ A,
                                                    const ushort* __restrict__ Bt,
                                                    ushort* __restrict__ h1b, int M) {
  __shared__ ushort sA[64 * 40];   // [row][k] bf16, stride 40
  __shared__ ushort sB[256 * 40];  // [col][k] bf16, stride 40
  int t = threadIdx.x;
  int wave = t >> 6, lane = t & 63;
  int m0 = blockIdx.x * 64;
  int c = lane & 15, kg = lane >> 4;
  v4f acc[4][4];
#pragma unroll
  for (int a = 0; a < 4; a++)
#pragma unroll
    for (int b = 0; b < 4; b++) acc[a][b] = (v4f)(0.f);
  int arow = t >> 2;
  int akoff = (t & 3) * 8;
  bool aval = (m0 + arow) < M;
  const float* aptr = A + (size_t)(m0 + arow) * 256 + akoff;
  const ushort* bptr = Bt + (size_t)t * 256;
  for (int k0 = 0; k0 < 256; k0 += 32) {
    float4 v0 = make_float4(0.f, 0.f, 0.f, 0.f), v1 = v0;
    if (aval) { v0 = *(const float4*)(aptr + k0); v1 = *(const float4*)(aptr + k0 + 4); }
    ushort* dst = &sA[arow * 40 + akoff];
    dst[0] = f2bf(v0.x); dst[1] = f2bf(v0.y); dst[2] = f2bf(v0.z); dst[3] = f2bf(v0.w);
    dst[4] = f2bf(v1.x); dst[5] = f2bf(v1.y); dst[6] = f2bf(v1.z); dst[7] = f2bf(v1.w);
    *(v8s*)&sB[t * 40 + 0]  = *(const v8s*)(bptr + k0 + 0);
    *(v8s*)&sB[t * 40 + 8]  = *(const v8s*)(bptr + k0 + 8);
    *(v8s*)&sB[t * 40 + 16] = *(const v8s*)(bptr + k0 + 16);
    *(v8s*)&sB[t * 40 + 24] = *(const v8s*)(bptr + k0 + 24);
    __syncthreads();
    v8s af[4], bfr[4];
#pragma unroll
    for (int mt = 0; mt < 4; mt++) af[mt] = *(v8s*)&sA[(mt * 16 + c) * 40 + kg * 8];
#pragma unroll
    for (int nt = 0; nt < 4; nt++) bfr[nt] = *(v8s*)&sB[(wave * 64 + nt * 16 + c) * 40 + kg * 8];
#pragma unroll
    for (int mt = 0; mt < 4; mt++)
#pragma unroll
      for (int nt = 0; nt < 4; nt++)
        acc[mt][nt] = __builtin_amdgcn_mfma_f32_16x16x32_bf16(af[mt], bfr[nt], acc[mt][nt], 0, 0, 0);
    __syncthreads();
  }
  // C/D layout: col = lane&15, row = (lane>>4)*4 + reg
#pragma unroll
  for (int mt = 0; mt < 4; mt++) {
#pragma unroll
    for (int i = 0; i < 4; i++) {
      int m = m0 + mt * 16 + kg * 4 + i;
      if (m < M) {
#pragma unroll
        for (int nt = 0; nt < 4; nt++)
          h1b[(size_t)m * 256 + wave * 64 + nt * 16 + c] = f2bf(acc[mt][nt][i]);
      }
    }
  }
}

// a_src/a_dst for conv1 from bf16 h1.
__global__ void k_attn1(const ushort* __restrict__ h1b, const float* __restrict__ as1,
                        const float* __restrict__ ad1, float* __restrict__ asv,
                        float* __restrict__ adv, int N) {
  int i = blockIdx.x * blockDim.x + threadIdx.x;
  if (i >= N * 8) return;
  int n = i >> 3, h = i & 7;
  const ushort* hp = h1b + (size_t)n * 256 + h * 32;
  const float* ap = as1 + h * 32;
  const float* dp = ad1 + h * 32;
  float s1 = 0.f, s2 = 0.f;
#pragma unroll
  for (int c = 0; c < 32; c++) {
    float v = bf2f(hp[c]);
    s1 += v * ap[c];
    s2 += v * dp[c];
  }
  asv[i] = s1;
  adv[i] = s2;
}

// ------------------------------------------------- conv1: one wave per node
__global__ __launch_bounds__(64) void k_conv1(
    const int* __restrict__ row_ptr, const int* __restrict__ csr_src,
    const float* __restrict__ csr_aed1, const float* __restrict__ asv,
    const float* __restrict__ adv, const ushort* __restrict__ h1b,
    const float* __restrict__ b1, float* __restrict__ h2, int N) {
  int n = blockIdx.x;
  int lane = threadIdx.x;
  int h = lane >> 3;
  int sub = lane & 7;
  __shared__ float sw[64 * 8];
  __shared__ int ssrc[64];
  __shared__ float sm[8], sl[8], sadv[8];
  int begin = row_ptr[n], end = row_ptr[n + 1];
  if (lane < 8) { sm[lane] = -FLT_MAX; sl[lane] = 0.f; sadv[lane] = adv[(size_t)n * 8 + lane]; }
  float4 acc = make_float4(0.f, 0.f, 0.f, 0.f);
  for (int cs = begin; cs < end; cs += 64) {
    int c = min(64, end - cs);
    __syncthreads();
    if (lane < c) ssrc[lane] = csr_src[cs + lane];
    __syncthreads();
    for (int idx = lane; idx < c * 8; idx += 64) {
      int el = idx >> 3, hh = idx & 7;
      float a = asv[(size_t)ssrc[el] * 8 + hh] + sadv[hh] +
                csr_aed1[(size_t)(cs + el) * 8 + hh];
      a = a > 0.f ? a : 0.2f * a;
      sw[idx] = a;
    }
    __syncthreads();
    float mloc = -FLT_MAX;
    for (int el = sub; el < c; el += 8) mloc = fmaxf(mloc, sw[el * 8 + h]);
#pragma unroll
    for (int o = 1; o < 8; o <<= 1) mloc = fmaxf(mloc, __shfl_xor(mloc, o));
    float mold = sm[h];
    float mnew = fmaxf(mold, mloc);
    float scale = __expf(mold - mnew);
    float lloc = 0.f;
    for (int el = sub; el < c; el += 8) {
      float w = __expf(sw[el * 8 + h] - mnew);
      sw[el * 8 + h] = w;
      lloc += w;
    }
#pragma unroll
    for (int o = 1; o < 8; o <<= 1) lloc += __shfl_xor(lloc, o);
    __syncthreads();
    if (sub == 0) { sm[h] = mnew; sl[h] = sl[h] * scale + lloc; }
    acc.x *= scale; acc.y *= scale; acc.z *= scale; acc.w *= scale;
    for (int el = 0; el < c; el++) {
      float w = sw[el * 8 + h];
      ushort4 hv = *(const ushort4*)(h1b + (size_t)ssrc[el] * 256 + lane * 4);
      acc.x += w * bf2f(hv.x);
      acc.y += w * bf2f(hv.y);
      acc.z += w * bf2f(hv.z);
      acc.w += w * bf2f(hv.w);
    }
  }
  __syncthreads();
  float inv = 1.f / (sl[h] + 1e-16f);
  float4 bv = *(const float4*)(b1 + lane * 4);
  float4 o4;
  o4.x = fmaxf(acc.x * inv + bv.x, 0.f);
  o4.y = fmaxf(acc.y * inv + bv.y, 0.f);
  o4.z = fmaxf(acc.z * inv + bv.z, 0.f);
  o4.w = fmaxf(acc.w * inv + bv.w, 0.f);
  *(float4*)(h2 + (size_t)n * 256 + lane * 4) = o4;
}

// g2 = h2 @ W2 (256 -> 32), 8 nodes/block; fused asv2/adv2 epilogue.
__global__ __launch_bounds__(256) void k_gemm2(const float* __restrict__ h2,
                                               const float* __restrict__ W2,
                                               const float* __restrict__ as2,
                                               const float* __restrict__ ad2,
                                               float* __restrict__ g2,
                                               float* __restrict__ asv2,
                                               float* __restrict__ adv2, int N) {
  __shared__ float xs[8 * 256];
  __shared__ float sas[32], sad[32];
  int t = threadIdx.x;
  if (t < 32) { sas[t] = as2[t]; sad[t] = ad2[t]; }
  int n0 = blockIdx.x * 8;
  for (int idx = t; idx < 8 * 256; idx += 256) {
    int node = n0 + (idx >> 8);
    xs[idx] = (node < N) ? h2[(size_t)node * 256 + (idx & 255)] : 0.f;
  }
  __syncthreads();
  int j = t >> 5, cc = t & 31;
  int node = n0 + j;
  float acc = 0.f;
#pragma unroll 8
  for (int k = 0; k < 256; k++) acc += xs[j * 256 + k] * W2[k * 32 + cc];
  float s1 = acc * sas[cc], s2 = acc * sad[cc];
#pragma unroll
  for (int o = 1; o < 32; o <<= 1) {
    s1 += __shfl_xor(s1, o);
    s2 += __shfl_xor(s2, o);
  }
  if (node < N) {
    g2[(size_t)node * 32 + cc] = acc;
    if (cc == 0) { asv2[node] = s1; adv2[node] = s2; }
  }
}

// ------------------------------------------------- conv2: one wave per node
__global__ __launch_bounds__(64) void k_conv2(
    const int* __restrict__ row_ptr, const int* __restrict__ csr_src,
    const float* __restrict__ csr_aed2, const float* __restrict__ asv2,
    const float* __restrict__ adv2, const float* __restrict__ g2,
    const float* __restrict__ b2, float* __restrict__ out, int N) {
  int n = blockIdx.x;
  int lane = threadIdx.x;
  int sub = lane >> 3, q = lane & 7;
  __shared__ float sw[64];
  __shared__ int ssrc[64];
  int begin = row_ptr[n], end = row_ptr[n + 1];
  float advn = adv2[n];
  float m = -FLT_MAX, l = 0.f;
  float4 acc = make_float4(0.f, 0.f, 0.f, 0.f);
  for (int cs = begin; cs < end; cs += 64) {
    int c = min(64, end - cs);
    __syncthreads();
    float a = -FLT_MAX;
    if (lane < c) {
      int s = csr_src[cs + lane];
      ssrc[lane] = s;
      a = asv2[s] + advn + csr_aed2[cs + lane];
      a = a > 0.f ? a : 0.2f * a;
    }
    float cm = a;
#pragma unroll
    for (int o = 1; o < 64; o <<= 1) cm = fmaxf(cm, __shfl_xor(cm, o));
    float nm = fmaxf(m, cm);
    float sc = __expf(m - nm);
    float w = (lane < c) ? __expf(a - nm) : 0.f;
    float cl = w;
#pragma unroll
    for (int o = 1; o < 64; o <<= 1) cl += __shfl_xor(cl, o);
    l = l * sc + cl;
    m = nm;
    sw[lane] = w;
    __syncthreads();
    acc.x *= sc; acc.y *= sc; acc.z *= sc; acc.w *= sc;
    for (int el = sub; el < c; el += 8) {
      float w2 = sw[el];
      const float4 gv = *(const float4*)(g2 + (size_t)ssrc[el] * 32 + q * 4);
      acc.x += w2 * gv.x; acc.y += w2 * gv.y; acc.z += w2 * gv.z; acc.w += w2 * gv.w;
    }
  }
#pragma unroll
  for (int o = 8; o < 64; o <<= 1) {
    acc.x += __shfl_xor(acc.x, o);
    acc.y += __shfl_xor(acc.y, o);
    acc.z += __shfl_xor(acc.z, o);
    acc.w += __shfl_xor(acc.w, o);
  }
  if (lane < 8) {
    float inv = 1.f / (l + 1e-16f);
    float4 bv = *(const float4*)(b2 + lane * 4);
    float4 o4;
    o4.x = acc.x * inv + bv.x;
    o4.y = acc.y * inv + bv.y;
    o4.z = acc.z * inv + bv.z;
    o4.w = acc.w * inv + bv.w;
    *(float4*)(out + (size_t)n * 32 + lane * 4) = o4;
  }
}

// ---------------------------------------------------------------- launch
extern "C" void kernel_launch(void* const* d_in, const int* in_sizes, int n_in,
                              void* d_out, int out_size, void* d_ws, size_t ws_size,
                              hipStream_t stream) {
  (void)n_in; (void)out_size; (void)ws_size;
  const float* x   = (const float*)d_in[0];
  const int*   ei  = (const int*)d_in[1];
  const float* ea  = (const float*)d_in[2];
  const float* Wse = (const float*)d_in[3];
  const float* bse = (const float*)d_in[4];
  const float* W1  = (const float*)d_in[5];
  const float* as1 = (const float*)d_in[6];
  const float* ad1 = (const float*)d_in[7];
  const float* We1 = (const float*)d_in[8];
  const float* ae1 = (const float*)d_in[9];
  const float* b1  = (const float*)d_in[10];
  const float* W2  = (const float*)d_in[11];
  const float* as2 = (const float*)d_in[12];
  const float* ad2 = (const float*)d_in[13];
  const float* We2 = (const float*)d_in[14];
  const float* ae2 = (const float*)d_in[15];
  const float* b2  = (const float*)d_in[16];
  const int N = in_sizes[0] / 256;
  const int E = in_sizes[1] / 2;
  const int* src = ei;
  const int* dst = ei + E;

  char* base = (char*)d_ws;
  size_t off = 0;
  auto alloc = [&](size_t bytes) -> char* {
    off = (off + 255) & ~(size_t)255;
    char* p = base + off;
    off += bytes;
    return p;
  };
  int*   deg      = (int*)alloc((size_t)N * 4);
  int*   cursor   = (int*)alloc((size_t)N * 4);
  size_t zero_bytes = (size_t)((char*)(cursor + N) - (char*)deg);
  int* row_ptr    = (int*)alloc((size_t)(N + 1) * 4);
  int* selfpos    = (int*)alloc((size_t)N * 4);
  int* csr_src    = (int*)alloc((size_t)(E + N) * 4);
  float* aed1_lin = (float*)alloc((size_t)E * 8 * 4);
  float* aed2_lin = (float*)alloc((size_t)E * 4);
  float* csr_aed1 = (float*)alloc((size_t)(E + N) * 8 * 4);
  float* csr_aed2 = (float*)alloc((size_t)(E + N) * 4);
  ushort* W1T     = (ushort*)alloc((size_t)256 * 256 * 2);
  ushort* h1b     = (ushort*)alloc((size_t)N * 256 * 2);
  float* asv1     = (float*)alloc((size_t)N * 8 * 4);
  float* adv1     = (float*)alloc((size_t)N * 8 * 4);
  float* h2       = (float*)alloc((size_t)N * 256 * 4);
  float* g2       = (float*)alloc((size_t)N * 32 * 4);
  float* asv2     = (float*)alloc((size_t)N * 4);
  float* adv2     = (float*)alloc((size_t)N * 4);
  float* M1       = (float*)alloc(64 * 4);
  float* m2       = (float*)alloc(8 * 4);

  hipMemsetAsync(deg, 0, zero_bytes, stream);
  k_deg<<<(E + 255) / 256, 256, 0, stream>>>(dst, deg, E);
  k_scan<<<1, 1024, 0, stream>>>(deg, row_ptr, N);
  k_prep<<<1, 128, 0, stream>>>(We1, ae1, We2, ae2, M1, m2);
  k_edge_fused<<<(E + 255) / 256, 256, 0, stream>>>(ea, Wse, bse, M1, m2, aed1_lin, aed2_lin, E);
  k_scatter<<<(E + N + 255) / 256, 256, 0, stream>>>(src, dst, row_ptr, cursor,
                                                     aed1_lin, aed2_lin,
                                                     csr_src, csr_aed1, csr_aed2, selfpos, E, N);
  k_selfmean<<<(N * 8 + 255) / 256, 256, 0, stream>>>(row_ptr, selfpos, csr_aed1, csr_aed2, N);
  k_transpose<<<64, 256, 0, stream>>>(W1, W1T);
  k_gemm1_mfma<<<(N + 63) / 64, 256, 0, stream>>>(x, W1T, h1b, N);
  k_attn1<<<(N * 8 + 255) / 256, 256, 0, stream>>>(h1b, as1, ad1, asv1, adv1, N);
  k_conv1<<<N, 64, 0, stream>>>(row_ptr, csr_src, csr_aed1, asv1, adv1, h1b, b1, h2, N);
  k_gemm2<<<(N + 7) / 8, 256, 0, stream>>>(h2, W2, as2, ad2, g2, asv2, adv2, N);
  k_conv2<<<N, 64, 0, stream>>>(row_ptr, csr_src, csr_aed2, asv2, adv2, g2, b2, (float*)d_out, N);
}

// Round 5
// 266.902 us; speedup vs baseline: 1.7631x; 1.0371x over previous
//
#include <hip/hip_runtime.h>
#include <float.h>

// Model constants: N=20000, E=320000, F_IN=256, HID=32, HEADS=8, EDGE_DIM=8

typedef short v8s __attribute__((ext_vector_type(8)));
typedef float v4f __attribute__((ext_vector_type(4)));

__device__ __forceinline__ ushort f2bf(float f) {
  unsigned u = __float_as_uint(f);
  u = (u + 0x7FFF + ((u >> 16) & 1)) >> 16;
  return (ushort)u;
}
__device__ __forceinline__ float bf2f(ushort h) {
  return __uint_as_float(((unsigned)h) << 16);
}

// ---------------------------------------------------------------- CSR build
__global__ __launch_bounds__(1024) void k_scan(const int* __restrict__ deg,
                                               int* __restrict__ row_ptr, int N) {
  __shared__ int part[1024];
  int tid = threadIdx.x;
  int chunk = (N + 1023) / 1024;
  int lo = tid * chunk;
  if (lo > N) lo = N;
  int hi = lo + chunk;
  if (hi > N) hi = N;
  int s = 0;
  for (int i = lo; i < hi; i++) s += deg[i] + 1;
  part[tid] = s;
  __syncthreads();
  for (int off = 1; off < 1024; off <<= 1) {
    int v = 0;
    if (tid >= off) v = part[tid - off];
    __syncthreads();
    part[tid] += v;
    __syncthreads();
  }
  int base = part[tid] - s;  // exclusive prefix
  for (int i = lo; i < hi; i++) { row_ptr[i] = base; base += deg[i] + 1; }
  if (tid == 1023) row_ptr[N] = part[1023];
}

// Scatter edges + self loops into CSR order by dst; aed values carried along.
__global__ void k_scatter(const int* __restrict__ src, const int* __restrict__ dst,
                          const int* __restrict__ row_ptr, int* __restrict__ cursor,
                          const float* __restrict__ aed1_lin, const float* __restrict__ aed2_lin,
                          int* __restrict__ csr_src, float* __restrict__ csr_aed1,
                          float* __restrict__ csr_aed2, int* __restrict__ selfpos,
                          int E, int N) {
  int i = blockIdx.x * blockDim.x + threadIdx.x;
  if (i >= E + N) return;
  if (i < E) {
    int d = dst[i];
    int pos = row_ptr[d] + atomicAdd(&cursor[d], 1);
    csr_src[pos] = src[i];
    const float4* a4 = (const float4*)(aed1_lin + (size_t)i * 8);
    *(float4*)(csr_aed1 + (size_t)pos * 8)     = a4[0];
    *(float4*)(csr_aed1 + (size_t)pos * 8 + 4) = a4[1];
    csr_aed2[pos] = aed2_lin[i];
  } else {
    int n = i - E;
    int pos = row_ptr[n] + atomicAdd(&cursor[n], 1);
    csr_src[pos] = n;
    selfpos[n] = pos;  // aed filled later by k_selfmean
  }
}

// ------------------------------------- prep (block 64) + W1 transpose (blocks 0-63)
// M1[k][h] = sum_c We1[k][h*32+c]*ae1[h][c]; m2[k] = sum_c We2[k][c]*ae2[c];
// W1T[n][k] = bf16(W1[k][n]).
__global__ __launch_bounds__(256) void k_prep_trans(const float* __restrict__ W1,
                                                    const float* __restrict__ We1,
                                                    const float* __restrict__ ae1,
                                                    const float* __restrict__ We2,
                                                    const float* __restrict__ ae2,
                                                    ushort* __restrict__ Bt,
                                                    float* __restrict__ M1,
                                                    float* __restrict__ m2) {
  if (blockIdx.x == 64) {
    int t = threadIdx.x;
    if (t < 64) {
      int k = t >> 3, h = t & 7;
      float s = 0.f;
      for (int c = 0; c < 32; c++) s += We1[k * 256 + h * 32 + c] * ae1[h * 32 + c];
      M1[k * 8 + h] = s;
    } else if (t < 72) {
      int k = t - 64;
      float s = 0.f;
      for (int c = 0; c < 32; c++) s += We2[k * 32 + c] * ae2[c];
      m2[k] = s;
    }
    return;
  }
  __shared__ float tile[32][33];
  int bx = blockIdx.x & 7, by = blockIdx.x >> 3;
  int tx = threadIdx.x & 31, ty = threadIdx.x >> 5;
  for (int r = ty; r < 32; r += 8)
    tile[r][tx] = W1[(size_t)(by * 32 + r) * 256 + bx * 32 + tx];
  __syncthreads();
  for (int r = ty; r < 32; r += 8)
    Bt[(size_t)(bx * 32 + r) * 256 + by * 32 + tx] = f2bf(tile[tx][r]);
}

// ------------------------------- fused edge logits + degree count (one pass)
__global__ void k_edge_fused(const float* __restrict__ ea, const int* __restrict__ dst,
                             const float* __restrict__ Wse, const float* __restrict__ bse,
                             const float* __restrict__ M1, const float* __restrict__ m2,
                             float* __restrict__ aed1, float* __restrict__ aed2,
                             int* __restrict__ deg, int E) {
  __shared__ float sW[16], sb[8], sM[64], sm2[8];
  int t = threadIdx.x;
  if (t < 16) sW[t] = Wse[t];
  if (t < 8) sb[t] = bse[t];
  if (t < 64) sM[t] = M1[t];
  if (t >= 64 && t < 72) sm2[t - 64] = m2[t - 64];
  __syncthreads();
  int e = blockIdx.x * blockDim.x + t;
  if (e >= E) return;
  atomicAdd(&deg[dst[e]], 1);
  float2 av = ((const float2*)ea)[e];
  float e8[8];
#pragma unroll
  for (int k = 0; k < 8; k++)
    e8[k] = fmaxf(av.x * sW[k] + av.y * sW[8 + k] + sb[k], 0.f);
  float o[8];
#pragma unroll
  for (int h = 0; h < 8; h++) {
    float s = 0.f;
#pragma unroll
    for (int k = 0; k < 8; k++) s += e8[k] * sM[k * 8 + h];
    o[h] = s;
  }
  *(float4*)(aed1 + (size_t)e * 8)     = make_float4(o[0], o[1], o[2], o[3]);
  *(float4*)(aed1 + (size_t)e * 8 + 4) = make_float4(o[4], o[5], o[6], o[7]);
  float s2 = 0.f;
#pragma unroll
  for (int k = 0; k < 8; k++) s2 += e8[k] * sm2[k];
  aed2[e] = s2;
}

// Self-loop logits: mean of the row's real-edge logits, written at selfpos.
__global__ void k_selfmean(const int* __restrict__ row_ptr, const int* __restrict__ selfpos,
                           float* __restrict__ csr_aed1, float* __restrict__ csr_aed2,
                           int N) {
  int i = blockIdx.x * blockDim.x + threadIdx.x;
  if (i >= N * 8) return;
  int n = i >> 3, h = i & 7;
  int begin = row_ptr[n], end = row_ptr[n + 1];
  int sp = selfpos[n];
  int deg = end - begin - 1;
  float inv = 1.f / (float)(deg > 1 ? deg : 1);
  float s = 0.f, s2 = 0.f;
  for (int p = begin; p < end; p++) {
    if (p == sp) continue;
    s += csr_aed1[(size_t)p * 8 + h];
    if (h == 0) s2 += csr_aed2[p];
  }
  csr_aed1[(size_t)sp * 8 + h] = s * inv;
  if (h == 0) csr_aed2[sp] = s2 * inv;
}

// ---------------------------------------------------------------- GEMM1 (MFMA bf16)
// h1b = bf16(x @ W1); fused attn1 epilogue: asv/adv per (node, head).
// 64 rows x 256 cols per block; 4 waves, each 64 cols (= heads 2w, 2w+1).
__global__ __launch_bounds__(256) void k_gemm1_mfma(const float* __restrict__ A,
                                                    const ushort* __restrict__ Bt,
                                                    const float* __restrict__ as1,
                                                    const float* __restrict__ ad1,
                                                    ushort* __restrict__ h1b,
                                                    float* __restrict__ asv,
                                                    float* __restrict__ adv, int M) {
  __shared__ ushort sA[64 * 40];   // [row][k] bf16, stride 40
  __shared__ ushort sB[256 * 40];  // [col][k] bf16, stride 40
  __shared__ float sas[256], sad[256];
  int t = threadIdx.x;
  int wave = t >> 6, lane = t & 63;
  int m0 = blockIdx.x * 64;
  int c = lane & 15, kg = lane >> 4;
  sas[t] = as1[t];
  sad[t] = ad1[t];
  v4f acc[4][4];
#pragma unroll
  for (int a = 0; a < 4; a++)
#pragma unroll
    for (int b = 0; b < 4; b++) acc[a][b] = (v4f)(0.f);
  int arow = t >> 2;
  int akoff = (t & 3) * 8;
  bool aval = (m0 + arow) < M;
  const float* aptr = A + (size_t)(m0 + arow) * 256 + akoff;
  const ushort* bptr = Bt + (size_t)t * 256;
  for (int k0 = 0; k0 < 256; k0 += 32) {
    float4 v0 = make_float4(0.f, 0.f, 0.f, 0.f), v1 = v0;
    if (aval) { v0 = *(const float4*)(aptr + k0); v1 = *(const float4*)(aptr + k0 + 4); }
    ushort* dst = &sA[arow * 40 + akoff];
    dst[0] = f2bf(v0.x); dst[1] = f2bf(v0.y); dst[2] = f2bf(v0.z); dst[3] = f2bf(v0.w);
    dst[4] = f2bf(v1.x); dst[5] = f2bf(v1.y); dst[6] = f2bf(v1.z); dst[7] = f2bf(v1.w);
    *(v8s*)&sB[t * 40 + 0]  = *(const v8s*)(bptr + k0 + 0);
    *(v8s*)&sB[t * 40 + 8]  = *(const v8s*)(bptr + k0 + 8);
    *(v8s*)&sB[t * 40 + 16] = *(const v8s*)(bptr + k0 + 16);
    *(v8s*)&sB[t * 40 + 24] = *(const v8s*)(bptr + k0 + 24);
    __syncthreads();
    v8s af[4], bfr[4];
#pragma unroll
    for (int mt = 0; mt < 4; mt++) af[mt] = *(v8s*)&sA[(mt * 16 + c) * 40 + kg * 8];
#pragma unroll
    for (int nt = 0; nt < 4; nt++) bfr[nt] = *(v8s*)&sB[(wave * 64 + nt * 16 + c) * 40 + kg * 8];
#pragma unroll
    for (int mt = 0; mt < 4; mt++)
#pragma unroll
      for (int nt = 0; nt < 4; nt++)
        acc[mt][nt] = __builtin_amdgcn_mfma_f32_16x16x32_bf16(af[mt], bfr[nt], acc[mt][nt], 0, 0, 0);
    __syncthreads();
  }
  // C/D layout: col = lane&15 (=c), row = kg*4 + reg
  int colbase = wave * 64;
#pragma unroll
  for (int mt = 0; mt < 4; mt++) {
#pragma unroll
    for (int i = 0; i < 4; i++) {
      int m = m0 + mt * 16 + kg * 4 + i;
      if (m < M) {
#pragma unroll
        for (int nt = 0; nt < 4; nt++)
          h1b[(size_t)m * 256 + colbase + nt * 16 + c] = f2bf(acc[mt][nt][i]);
      }
      // fused attn1: head 2*wave (nt 0,1), head 2*wave+1 (nt 2,3)
      float s1a = acc[mt][0][i] * sas[colbase + c]      + acc[mt][1][i] * sas[colbase + 16 + c];
      float s2a = acc[mt][0][i] * sad[colbase + c]      + acc[mt][1][i] * sad[colbase + 16 + c];
      float s1b = acc[mt][2][i] * sas[colbase + 32 + c] + acc[mt][3][i] * sas[colbase + 48 + c];
      float s2b = acc[mt][2][i] * sad[colbase + 32 + c] + acc[mt][3][i] * sad[colbase + 48 + c];
#pragma unroll
      for (int o = 1; o < 16; o <<= 1) {
        s1a += __shfl_xor(s1a, o);
        s2a += __shfl_xor(s2a, o);
        s1b += __shfl_xor(s1b, o);
        s2b += __shfl_xor(s2b, o);
      }
      if (c == 0 && m < M) {
        asv[(size_t)m * 8 + 2 * wave]     = s1a;
        adv[(size_t)m * 8 + 2 * wave]     = s2a;
        asv[(size_t)m * 8 + 2 * wave + 1] = s1b;
        adv[(size_t)m * 8 + 2 * wave + 1] = s2b;
      }
    }
  }
}

// ------------------------------------------------- conv1: one wave per node
// h2b = bf16(relu(out + b1)).
__global__ __launch_bounds__(64) void k_conv1(
    const int* __restrict__ row_ptr, const int* __restrict__ csr_src,
    const float* __restrict__ csr_aed1, const float* __restrict__ asv,
    const float* __restrict__ adv, const ushort* __restrict__ h1b,
    const float* __restrict__ b1, ushort* __restrict__ h2b, int N) {
  int n = blockIdx.x;
  int lane = threadIdx.x;
  int h = lane >> 3;
  int sub = lane & 7;
  __shared__ float sw[64 * 8];
  __shared__ int ssrc[64];
  __shared__ float sm[8], sl[8], sadv[8];
  int begin = row_ptr[n], end = row_ptr[n + 1];
  if (lane < 8) { sm[lane] = -FLT_MAX; sl[lane] = 0.f; sadv[lane] = adv[(size_t)n * 8 + lane]; }
  float4 acc = make_float4(0.f, 0.f, 0.f, 0.f);
  for (int cs = begin; cs < end; cs += 64) {
    int c = min(64, end - cs);
    __syncthreads();
    if (lane < c) ssrc[lane] = csr_src[cs + lane];
    __syncthreads();
    for (int idx = lane; idx < c * 8; idx += 64) {
      int el = idx >> 3, hh = idx & 7;
      float a = asv[(size_t)ssrc[el] * 8 + hh] + sadv[hh] +
                csr_aed1[(size_t)(cs + el) * 8 + hh];
      a = a > 0.f ? a : 0.2f * a;
      sw[idx] = a;
    }
    __syncthreads();
    float mloc = -FLT_MAX;
    for (int el = sub; el < c; el += 8) mloc = fmaxf(mloc, sw[el * 8 + h]);
#pragma unroll
    for (int o = 1; o < 8; o <<= 1) mloc = fmaxf(mloc, __shfl_xor(mloc, o));
    float mold = sm[h];
    float mnew = fmaxf(mold, mloc);
    float scale = __expf(mold - mnew);
    float lloc = 0.f;
    for (int el = sub; el < c; el += 8) {
      float w = __expf(sw[el * 8 + h] - mnew);
      sw[el * 8 + h] = w;
      lloc += w;
    }
#pragma unroll
    for (int o = 1; o < 8; o <<= 1) lloc += __shfl_xor(lloc, o);
    __syncthreads();
    if (sub == 0) { sm[h] = mnew; sl[h] = sl[h] * scale + lloc; }
    acc.x *= scale; acc.y *= scale; acc.z *= scale; acc.w *= scale;
    for (int el = 0; el < c; el++) {
      float w = sw[el * 8 + h];
      ushort4 hv = *(const ushort4*)(h1b + (size_t)ssrc[el] * 256 + lane * 4);
      acc.x += w * bf2f(hv.x);
      acc.y += w * bf2f(hv.y);
      acc.z += w * bf2f(hv.z);
      acc.w += w * bf2f(hv.w);
    }
  }
  __syncthreads();
  float inv = 1.f / (sl[h] + 1e-16f);
  float4 bv = *(const float4*)(b1 + lane * 4);
  ushort4 o4;
  o4.x = f2bf(fmaxf(acc.x * inv + bv.x, 0.f));
  o4.y = f2bf(fmaxf(acc.y * inv + bv.y, 0.f));
  o4.z = f2bf(fmaxf(acc.z * inv + bv.z, 0.f));
  o4.w = f2bf(fmaxf(acc.w * inv + bv.w, 0.f));
  *(ushort4*)(h2b + (size_t)n * 256 + lane * 4) = o4;
}

// g2 = h2 @ W2 (256 -> 32), 8 nodes/block; fused asv2/adv2 epilogue.
__global__ __launch_bounds__(256) void k_gemm2(const ushort* __restrict__ h2b,
                                               const float* __restrict__ W2,
                                               const float* __restrict__ as2,
                                               const float* __restrict__ ad2,
                                               float* __restrict__ g2,
                                               float* __restrict__ asv2,
                                               float* __restrict__ adv2, int N) {
  __shared__ float xs[8 * 256];
  __shared__ float sas[32], sad[32];
  int t = threadIdx.x;
  if (t < 32) { sas[t] = as2[t]; sad[t] = ad2[t]; }
  int n0 = blockIdx.x * 8;
  for (int idx = t; idx < 8 * 256; idx += 256) {
    int node = n0 + (idx >> 8);
    xs[idx] = (node < N) ? bf2f(h2b[(size_t)node * 256 + (idx & 255)]) : 0.f;
  }
  __syncthreads();
  int j = t >> 5, cc = t & 31;
  int node = n0 + j;
  float acc = 0.f;
#pragma unroll 8
  for (int k = 0; k < 256; k++) acc += xs[j * 256 + k] * W2[k * 32 + cc];
  float s1 = acc * sas[cc], s2 = acc * sad[cc];
#pragma unroll
  for (int o = 1; o < 32; o <<= 1) {
    s1 += __shfl_xor(s1, o);
    s2 += __shfl_xor(s2, o);
  }
  if (node < N) {
    g2[(size_t)node * 32 + cc] = acc;
    if (cc == 0) { asv2[node] = s1; adv2[node] = s2; }
  }
}

// ------------------------------------------------- conv2: one wave per node
__global__ __launch_bounds__(64) void k_conv2(
    const int* __restrict__ row_ptr, const int* __restrict__ csr_src,
    const float* __restrict__ csr_aed2, const float* __restrict__ asv2,
    const float* __restrict__ adv2, const float* __restrict__ g2,
    const float* __restrict__ b2, float* __restrict__ out, int N) {
  int n = blockIdx.x;
  int lane = threadIdx.x;
  int sub = lane >> 3, q = lane & 7;
  __shared__ float sw[64];
  __shared__ int ssrc[64];
  int begin = row_ptr[n], end = row_ptr[n + 1];
  float advn = adv2[n];
  float m = -FLT_MAX, l = 0.f;
  float4 acc = make_float4(0.f, 0.f, 0.f, 0.f);
  for (int cs = begin; cs < end; cs += 64) {
    int c = min(64, end - cs);
    __syncthreads();
    float a = -FLT_MAX;
    if (lane < c) {
      int s = csr_src[cs + lane];
      ssrc[lane] = s;
      a = asv2[s] + advn + csr_aed2[cs + lane];
      a = a > 0.f ? a : 0.2f * a;
    }
    float cm = a;
#pragma unroll
    for (int o = 1; o < 64; o <<= 1) cm = fmaxf(cm, __shfl_xor(cm, o));
    float nm = fmaxf(m, cm);
    float sc = __expf(m - nm);
    float w = (lane < c) ? __expf(a - nm) : 0.f;
    float cl = w;
#pragma unroll
    for (int o = 1; o < 64; o <<= 1) cl += __shfl_xor(cl, o);
    l = l * sc + cl;
    m = nm;
    sw[lane] = w;
    __syncthreads();
    acc.x *= sc; acc.y *= sc; acc.z *= sc; acc.w *= sc;
    for (int el = sub; el < c; el += 8) {
      float w2 = sw[el];
      const float4 gv = *(const float4*)(g2 + (size_t)ssrc[el] * 32 + q * 4);
      acc.x += w2 * gv.x; acc.y += w2 * gv.y; acc.z += w2 * gv.z; acc.w += w2 * gv.w;
    }
  }
#pragma unroll
  for (int o = 8; o < 64; o <<= 1) {
    acc.x += __shfl_xor(acc.x, o);
    acc.y += __shfl_xor(acc.y, o);
    acc.z += __shfl_xor(acc.z, o);
    acc.w += __shfl_xor(acc.w, o);
  }
  if (lane < 8) {
    float inv = 1.f / (l + 1e-16f);
    float4 bv = *(const float4*)(b2 + lane * 4);
    float4 o4;
    o4.x = acc.x * inv + bv.x;
    o4.y = acc.y * inv + bv.y;
    o4.z = acc.z * inv + bv.z;
    o4.w = acc.w * inv + bv.w;
    *(float4*)(out + (size_t)n * 32 + lane * 4) = o4;
  }
}

// ---------------------------------------------------------------- launch
extern "C" void kernel_launch(void* const* d_in, const int* in_sizes, int n_in,
                              void* d_out, int out_size, void* d_ws, size_t ws_size,
                              hipStream_t stream) {
  (void)n_in; (void)out_size; (void)ws_size;
  const float* x   = (const float*)d_in[0];
  const int*   ei  = (const int*)d_in[1];
  const float* ea  = (const float*)d_in[2];
  const float* Wse = (const float*)d_in[3];
  const float* bse = (const float*)d_in[4];
  const float* W1  = (const float*)d_in[5];
  const float* as1 = (const float*)d_in[6];
  const float* ad1 = (const float*)d_in[7];
  const float* We1 = (const float*)d_in[8];
  const float* ae1 = (const float*)d_in[9];
  const float* b1  = (const float*)d_in[10];
  const float* W2  = (const float*)d_in[11];
  const float* as2 = (const float*)d_in[12];
  const float* ad2 = (const float*)d_in[13];
  const float* We2 = (const float*)d_in[14];
  const float* ae2 = (const float*)d_in[15];
  const float* b2  = (const float*)d_in[16];
  const int N = in_sizes[0] / 256;
  const int E = in_sizes[1] / 2;
  const int* src = ei;
  const int* dst = ei + E;

  char* base = (char*)d_ws;
  size_t off = 0;
  auto alloc = [&](size_t bytes) -> char* {
    off = (off + 255) & ~(size_t)255;
    char* p = base + off;
    off += bytes;
    return p;
  };
  int*   deg      = (int*)alloc((size_t)N * 4);
  int*   cursor   = (int*)alloc((size_t)N * 4);
  size_t zero_bytes = (size_t)((char*)(cursor + N) - (char*)deg);
  int* row_ptr    = (int*)alloc((size_t)(N + 1) * 4);
  int* selfpos    = (int*)alloc((size_t)N * 4);
  int* csr_src    = (int*)alloc((size_t)(E + N) * 4);
  float* aed1_lin = (float*)alloc((size_t)E * 8 * 4);
  float* aed2_lin = (float*)alloc((size_t)E * 4);
  float* csr_aed1 = (float*)alloc((size_t)(E + N) * 8 * 4);
  float* csr_aed2 = (float*)alloc((size_t)(E + N) * 4);
  ushort* W1T     = (ushort*)alloc((size_t)256 * 256 * 2);
  ushort* h1b     = (ushort*)alloc((size_t)N * 256 * 2);
  float* asv1     = (float*)alloc((size_t)N * 8 * 4);
  float* adv1     = (float*)alloc((size_t)N * 8 * 4);
  ushort* h2b     = (ushort*)alloc((size_t)N * 256 * 2);
  float* g2       = (float*)alloc((size_t)N * 32 * 4);
  float* asv2     = (float*)alloc((size_t)N * 4);
  float* adv2     = (float*)alloc((size_t)N * 4);
  float* M1       = (float*)alloc(64 * 4);
  float* m2       = (float*)alloc(8 * 4);

  hipMemsetAsync(deg, 0, zero_bytes, stream);
  k_prep_trans<<<65, 256, 0, stream>>>(W1, We1, ae1, We2, ae2, W1T, M1, m2);
  k_edge_fused<<<(E + 255) / 256, 256, 0, stream>>>(ea, dst, Wse, bse, M1, m2,
                                                    aed1_lin, aed2_lin, deg, E);
  k_scan<<<1, 1024, 0, stream>>>(deg, row_ptr, N);
  k_scatter<<<(E + N + 255) / 256, 256, 0, stream>>>(src, dst, row_ptr, cursor,
                                                     aed1_lin, aed2_lin,
                                                     csr_src, csr_aed1, csr_aed2, selfpos, E, N);
  k_selfmean<<<(N * 8 + 255) / 256, 256, 0, stream>>>(row_ptr, selfpos, csr_aed1, csr_aed2, N);
  k_gemm1_mfma<<<(N + 63) / 64, 256, 0, stream>>>(x, W1T, as1, ad1, h1b, asv1, adv1, N);
  k_conv1<<<N, 64, 0, stream>>>(row_ptr, csr_src, csr_aed1, asv1, adv1, h1b, b1, h2b, N);
  k_gemm2<<<(N + 7) / 8, 256, 0, stream>>>(h2b, W2, as2, ad2, g2, asv2, adv2, N);
  k_conv2<<<N, 64, 0, stream>>>(row_ptr, csr_src, csr_aed2, asv2, adv2, g2, b2, (float*)d_out, N);
}